// Round 1
// baseline (1331.098 us; speedup 1.0000x reference)
//
#include <hip/hip_runtime.h>

typedef unsigned short u16;
typedef __attribute__((ext_vector_type(8))) short short8;
typedef __attribute__((ext_vector_type(4))) float floatx4;
typedef __attribute__((ext_vector_type(4))) unsigned short u16x4;

#define NTOK 8192
#define DMODEL 512
#define DFF 2048
#define LSEQ 2048

__device__ __forceinline__ u16 f2bf(float f) {
    union { float f; unsigned u; } x; x.f = f;
    unsigned r = (x.u + 0x7fffu + ((x.u >> 16) & 1u)) >> 16;
    return (u16)r;
}

__device__ __forceinline__ float geluf(float x) {
    return 0.5f * x * (1.0f + erff(x * 0.70710678118654752f));
}

__device__ __forceinline__ void gload_lds16(const void* g, void* l) {
    __builtin_amdgcn_global_load_lds(
        (const __attribute__((address_space(1))) void*)g,
        (__attribute__((address_space(3))) void*)l,
        16, 0, 0);
}

// ---------------------------------------------------------------------------
// Weight f32 -> bf16 conversion (Wqkv | Wo | W1 | W2 packed)
// ---------------------------------------------------------------------------
__global__ __launch_bounds__(256) void cvt_w(const float* __restrict__ wq,
                                             const float* __restrict__ wo,
                                             const float* __restrict__ w1,
                                             const float* __restrict__ w2,
                                             u16* __restrict__ out) {
    int i = blockIdx.x * 256 + threadIdx.x;   // grid covers 3145728 exactly
    float v;
    if (i < 786432)       v = wq[i];
    else if (i < 1048576) v = wo[i - 786432];
    else if (i < 2097152) v = w1[i - 1048576];
    else                  v = w2[i - 2097152];
    out[i] = f2bf(v);
}

__global__ __launch_bounds__(256) void copy_f32(const float* __restrict__ a,
                                                float* __restrict__ b) {
    size_t i = ((size_t)blockIdx.x * 256 + threadIdx.x) * 4;
    *(floatx4*)&b[i] = *(const floatx4*)&a[i];
}

// ---------------------------------------------------------------------------
// LayerNorm over D=512, one wave per row. OUTF32: f32 out (router) else bf16.
// ---------------------------------------------------------------------------
template<bool OUTF32>
__global__ __launch_bounds__(256)
void ln_k(const float* __restrict__ x, const float* __restrict__ g,
          const float* __restrict__ bb, void* __restrict__ outp) {
    const int row = blockIdx.x * 4 + (threadIdx.x >> 6);
    const int lane = threadIdx.x & 63;
    const float* xr = x + (size_t)row * DMODEL;
    const int c0 = lane * 4, c1 = c0 + 256;
    floatx4 a = *(const floatx4*)&xr[c0];
    floatx4 b = *(const floatx4*)&xr[c1];
    float s = 0.f, sq = 0.f;
#pragma unroll
    for (int e = 0; e < 4; ++e) { s += a[e]; sq += a[e] * a[e]; }
#pragma unroll
    for (int e = 0; e < 4; ++e) { s += b[e]; sq += b[e] * b[e]; }
#pragma unroll
    for (int m = 32; m >= 1; m >>= 1) {
        s += __shfl_xor(s, m);
        sq += __shfl_xor(sq, m);
    }
    const float mean = s * (1.f / 512.f);
    const float rstd = rsqrtf(sq * (1.f / 512.f) - mean * mean + 1e-5f);
    floatx4 g0 = *(const floatx4*)&g[c0];
    floatx4 g1 = *(const floatx4*)&g[c1];
    floatx4 b0 = *(const floatx4*)&bb[c0];
    floatx4 b1 = *(const floatx4*)&bb[c1];
    floatx4 y0, y1;
#pragma unroll
    for (int e = 0; e < 4; ++e) {
        y0[e] = (a[e] - mean) * rstd * g0[e] + b0[e];
        y1[e] = (b[e] - mean) * rstd * g1[e] + b1[e];
    }
    if (OUTF32) {
        float* o = (float*)outp + (size_t)row * DMODEL;
        *(floatx4*)&o[c0] = y0;
        *(floatx4*)&o[c1] = y1;
    } else {
        u16* o = (u16*)outp + (size_t)row * DMODEL;
        u16x4 p0, p1;
#pragma unroll
        for (int e = 0; e < 4; ++e) { p0[e] = f2bf(y0[e]); p1[e] = f2bf(y1[e]); }
        *(u16x4*)&o[c0] = p0;
        *(u16x4*)&o[c1] = p1;
    }
}

// ---------------------------------------------------------------------------
// bf16 MFMA GEMM: C[M,N] = epi(A[M,K] @ Bw[N,K]^T + bias)
// Tile 128 x BN x 32, 256 threads (4 waves, 2x2), global_load_lds staging
// with XOR chunk swizzle for conflict-free ds_read_b128.
// EPI: 0 = bf16 out, 1 = bf16 gelu out, 2 = f32 out = res + v (dense),
//      3 = f32 out = keep ? res + v : old   (keep = depth[row] >= level)
// ---------------------------------------------------------------------------
template<int EPI, int BN>
__global__ __launch_bounds__(256, 2)
void gemm_bt(const u16* __restrict__ A, const u16* __restrict__ Bw,
             const float* __restrict__ bias,
             u16* __restrict__ Cb, float* __restrict__ Cf,
             const float* __restrict__ res, const float* __restrict__ depth,
             float level, int N, int K) {
    constexpr int NJ = BN / 32;
    __shared__ __align__(16) u16 As[128 * 32];
    __shared__ __align__(16) u16 Bs[BN * 32];
    const int tid = threadIdx.x;
    const int lane = tid & 63;
    const int w = tid >> 6;
    const int wm = (w >> 1) * 64;
    const int wn = (w & 1) * (BN / 2);
    const int mBase = blockIdx.x * 128;
    const int nBase = blockIdx.y * BN;
    const int q4 = lane >> 4, rl = lane & 15;

    floatx4 acc[4][NJ];
#pragma unroll
    for (int i = 0; i < 4; ++i)
#pragma unroll
        for (int j = 0; j < NJ; ++j) acc[i][j] = (floatx4){0.f, 0.f, 0.f, 0.f};

    // staging chunk mapping: chunk i -> LDS elems [i*8, i*8+8) == (row=i>>2, slot=i&3)
    // source chunk c = slot ^ ((row>>1)&3)  (bank-conflict swizzle)
    const int i0 = tid, i1 = tid + 256;
    const int ar0 = i0 >> 2, ac0 = ((i0 & 3) ^ ((i0 >> 3) & 3)) * 8;
    const int ar1 = i1 >> 2, ac1 = ((i1 & 3) ^ ((i1 >> 3) & 3)) * 8;
    const u16* pA0 = A + (size_t)(mBase + ar0) * K + ac0;
    const u16* pA1 = A + (size_t)(mBase + ar1) * K + ac1;
    const u16* pB0 = Bw + (size_t)(nBase + ar0) * K + ac0;
    const u16* pB1 = (BN == 128) ? Bw + (size_t)(nBase + ar1) * K + ac1 : pB0;
    u16* lA0 = &As[i0 * 8];
    u16* lA1 = &As[i1 * 8];
    u16* lB0 = &Bs[i0 * 8];
    u16* lB1 = (BN == 128) ? &Bs[i1 * 8] : lB0;

    for (int k0 = 0; k0 < K; k0 += 32) {
        gload_lds16(pA0, lA0);
        gload_lds16(pA1, lA1);
        gload_lds16(pB0, lB0);
        if (BN == 128) gload_lds16(pB1, lB1);
        pA0 += 32; pA1 += 32; pB0 += 32;
        if (BN == 128) pB1 += 32;
        __syncthreads();
        short8 af[4], bf[NJ];
#pragma unroll
        for (int t = 0; t < 4; ++t) {
            const int r = wm + t * 16 + rl;
            af[t] = *(const short8*)&As[r * 32 + (q4 ^ ((r >> 1) & 3)) * 8];
        }
#pragma unroll
        for (int t = 0; t < NJ; ++t) {
            const int r = wn + t * 16 + rl;
            bf[t] = *(const short8*)&Bs[r * 32 + (q4 ^ ((r >> 1) & 3)) * 8];
        }
#pragma unroll
        for (int ti = 0; ti < 4; ++ti)
#pragma unroll
            for (int tj = 0; tj < NJ; ++tj)
                acc[ti][tj] = __builtin_amdgcn_mfma_f32_16x16x32_bf16(
                    af[ti], bf[tj], acc[ti][tj], 0, 0, 0);
        __syncthreads();
    }

#pragma unroll
    for (int ti = 0; ti < 4; ++ti) {
        const int r0 = mBase + wm + ti * 16 + q4 * 4;
#pragma unroll
        for (int tj = 0; tj < NJ; ++tj) {
            const int c = nBase + wn + tj * 16 + rl;
            const float bv = bias[c];
#pragma unroll
            for (int rr = 0; rr < 4; ++rr) {
                const int r = r0 + rr;
                const float v = acc[ti][tj][rr] + bv;
                if (EPI == 0) {
                    Cb[(size_t)r * N + c] = f2bf(v);
                } else if (EPI == 1) {
                    Cb[(size_t)r * N + c] = f2bf(geluf(v));
                } else if (EPI == 2) {
                    Cf[(size_t)r * N + c] = res[(size_t)r * N + c] + v;
                } else {
                    if (depth[r] >= level)
                        Cf[(size_t)r * N + c] = res[(size_t)r * N + c] + v;
                }
            }
        }
    }
}

// ---------------------------------------------------------------------------
// Flash attention: WG = (qtile of 128 rows, bh). 4 waves, 32 q-rows each.
// dh = 64, heads = 8, qkv layout [token][1536] (q|k|v).
// ---------------------------------------------------------------------------
__global__ __launch_bounds__(256, 2)
void attn_k(const u16* __restrict__ qkv, u16* __restrict__ o) {
    const int qt = blockIdx.x;
    const int bh = blockIdx.y;
    const int b = bh >> 3, h = bh & 7;
    const int tid = threadIdx.x, lane = tid & 63, w = tid >> 6;
    const int tok0 = b * LSEQ;
    const int qrow0 = qt * 128 + w * 32;
    const int q4 = lane >> 4, rl = lane & 15;

    __shared__ __align__(16) u16 Kt[128 * 64];     // [kv][dh], chunk-swizzled
    __shared__ __align__(16) u16 Vt[64 * 136];     // [dh][kv], stride 136
    __shared__ __align__(16) u16 Pl[4][32 * 144];  // per-wave P, stride 144

    short8 qf[2][2];
#pragma unroll
    for (int rt = 0; rt < 2; ++rt)
#pragma unroll
        for (int ks = 0; ks < 2; ++ks)
            qf[rt][ks] = *(const short8*)&qkv[(size_t)(tok0 + qrow0 + rt * 16 + rl) * 1536
                                              + h * 64 + ks * 32 + q4 * 8];

    floatx4 oacc[2][4];
#pragma unroll
    for (int rt = 0; rt < 2; ++rt)
#pragma unroll
        for (int dt = 0; dt < 4; ++dt) oacc[rt][dt] = (floatx4){0.f, 0.f, 0.f, 0.f};
    float m_[2][4], l_[2][4];
#pragma unroll
    for (int rt = 0; rt < 2; ++rt)
#pragma unroll
        for (int rr = 0; rr < 4; ++rr) { m_[rt][rr] = -1e30f; l_[rt][rr] = 0.f; }

    const float sc = 0.125f * 1.4426950408889634f;  // (1/sqrt(64)) * log2(e)

    for (int kt = 0; kt < 16; ++kt) {
        const int kv0 = kt * 128;
        __syncthreads();
        // stage K [128][64] with chunk swizzle: slot = chunk ^ (row&7)
#pragma unroll
        for (int it = 0; it < 4; ++it) {
            const int i = it * 256 + tid;
            const int r = i >> 3;
            const int c = ((i & 7) ^ (r & 7)) * 8;
            gload_lds16(&qkv[(size_t)(tok0 + kv0 + r) * 1536 + 512 + h * 64 + c],
                        &Kt[i * 8]);
        }
        // stage V transposed: Vt[dh][kv]
        {
            const int c = tid & 63;
            const int r0 = (tid >> 6) * 4;
#pragma unroll
            for (int it = 0; it < 8; ++it) {
                const int r = r0 + it * 16;
                const u16* vp = &qkv[(size_t)(tok0 + kv0 + r) * 1536 + 1024 + h * 64 + c];
                u16x4 pk;
                pk[0] = vp[0]; pk[1] = vp[1536]; pk[2] = vp[3072]; pk[3] = vp[4608];
                *(u16x4*)&Vt[c * 136 + r] = pk;
            }
        }
        __syncthreads();

        // S = Q K^T (32 q-rows x 128 kv)
        floatx4 s[2][8];
#pragma unroll
        for (int rt = 0; rt < 2; ++rt)
#pragma unroll
            for (int ct = 0; ct < 8; ++ct) s[rt][ct] = (floatx4){0.f, 0.f, 0.f, 0.f};
#pragma unroll
        for (int ct = 0; ct < 8; ++ct) {
            const int r = ct * 16 + rl;
            short8 kf0 = *(const short8*)&Kt[r * 64 + ((q4)     ^ (r & 7)) * 8];
            short8 kf1 = *(const short8*)&Kt[r * 64 + ((4 + q4) ^ (r & 7)) * 8];
#pragma unroll
            for (int rt = 0; rt < 2; ++rt) {
                s[rt][ct] = __builtin_amdgcn_mfma_f32_16x16x32_bf16(qf[rt][0], kf0, s[rt][ct], 0, 0, 0);
                s[rt][ct] = __builtin_amdgcn_mfma_f32_16x16x32_bf16(qf[rt][1], kf1, s[rt][ct], 0, 0, 0);
            }
        }

        // online softmax
#pragma unroll
        for (int rt = 0; rt < 2; ++rt) {
            float mx[4], rs[4], alpha[4];
#pragma unroll
            for (int rr = 0; rr < 4; ++rr) {
                float v = s[rt][0][rr];
#pragma unroll
                for (int ct = 1; ct < 8; ++ct) v = fmaxf(v, s[rt][ct][rr]);
                mx[rr] = v;
            }
#pragma unroll
            for (int m = 1; m <= 8; m <<= 1)
#pragma unroll
                for (int rr = 0; rr < 4; ++rr)
                    mx[rr] = fmaxf(mx[rr], __shfl_xor(mx[rr], m));
#pragma unroll
            for (int rr = 0; rr < 4; ++rr) {
                const float mnew = fmaxf(m_[rt][rr], sc * mx[rr]);
                alpha[rr] = exp2f(m_[rt][rr] - mnew);
                m_[rt][rr] = mnew;
                rs[rr] = 0.f;
            }
#pragma unroll
            for (int ct = 0; ct < 8; ++ct)
#pragma unroll
                for (int rr = 0; rr < 4; ++rr) {
                    const float p = exp2f(fmaf(s[rt][ct][rr], sc, -m_[rt][rr]));
                    rs[rr] += p;
                    Pl[w][(rt * 16 + q4 * 4 + rr) * 144 + ct * 16 + rl] = f2bf(p);
                }
#pragma unroll
            for (int m = 1; m <= 8; m <<= 1)
#pragma unroll
                for (int rr = 0; rr < 4; ++rr) rs[rr] += __shfl_xor(rs[rr], m);
#pragma unroll
            for (int rr = 0; rr < 4; ++rr) {
                l_[rt][rr] = l_[rt][rr] * alpha[rr] + rs[rr];
#pragma unroll
                for (int dt = 0; dt < 4; ++dt) oacc[rt][dt][rr] *= alpha[rr];
            }
        }

        // O += P V  (Pl wave-private: compiler lgkmcnt ordering suffices)
#pragma unroll
        for (int ks = 0; ks < 4; ++ks) {
            short8 pf[2];
#pragma unroll
            for (int rt = 0; rt < 2; ++rt)
                pf[rt] = *(const short8*)&Pl[w][(rt * 16 + rl) * 144 + ks * 32 + q4 * 8];
#pragma unroll
            for (int dt = 0; dt < 4; ++dt) {
                short8 vf = *(const short8*)&Vt[(dt * 16 + rl) * 136 + ks * 32 + q4 * 8];
#pragma unroll
                for (int rt = 0; rt < 2; ++rt)
                    oacc[rt][dt] = __builtin_amdgcn_mfma_f32_16x16x32_bf16(pf[rt], vf, oacc[rt][dt], 0, 0, 0);
            }
        }
    }

#pragma unroll
    for (int rt = 0; rt < 2; ++rt)
#pragma unroll
        for (int rr = 0; rr < 4; ++rr) {
            const float inv = 1.0f / l_[rt][rr];
            const size_t row = tok0 + qrow0 + rt * 16 + q4 * 4 + rr;
#pragma unroll
            for (int dt = 0; dt < 4; ++dt)
                o[row * DMODEL + h * 64 + dt * 16 + rl] = f2bf(oacc[rt][dt][rr] * inv);
        }
}

// ---------------------------------------------------------------------------
// Router GEMM1 (fp64 accumulation): rr = gelu(rh @ Rw1^T + Rb1)
// 64x64 tile, BK=32, LDS holds f64-converted tiles.
// ---------------------------------------------------------------------------
__global__ __launch_bounds__(256)
void router_gemm1(const float* __restrict__ A, const float* __restrict__ W,
                  const float* __restrict__ bias, float* __restrict__ out) {
    __shared__ double Asd[64][33];
    __shared__ double Bsd[64][33];
    const int tid = threadIdx.x;
    const int tx = tid & 15, ty = tid >> 4;
    const int mb = blockIdx.x * 64, nb = blockIdx.y * 64;
    double acc[4][4] = {};
    for (int k0 = 0; k0 < 512; k0 += 32) {
#pragma unroll
        for (int i = 0; i < 8; ++i) {
            const int e = tid + i * 256;
            const int r = e >> 5, c = e & 31;
            Asd[r][c] = (double)A[(size_t)(mb + r) * 512 + k0 + c];
            Bsd[r][c] = (double)W[(size_t)(nb + r) * 512 + k0 + c];
        }
        __syncthreads();
        for (int kk = 0; kk < 32; ++kk) {
            double av[4], bv[4];
#pragma unroll
            for (int i = 0; i < 4; ++i) av[i] = Asd[ty * 4 + i][kk];
#pragma unroll
            for (int j = 0; j < 4; ++j) bv[j] = Bsd[tx * 4 + j][kk];
#pragma unroll
            for (int i = 0; i < 4; ++i)
#pragma unroll
                for (int j = 0; j < 4; ++j)
                    acc[i][j] = fma(av[i], bv[j], acc[i][j]);
        }
        __syncthreads();
    }
#pragma unroll
    for (int i = 0; i < 4; ++i) {
        const int r = mb + ty * 4 + i;
#pragma unroll
        for (int j = 0; j < 4; ++j) {
            const int c = nb + tx * 4 + j;
            out[(size_t)r * 512 + c] = geluf((float)(acc[i][j] + (double)bias[c]));
        }
    }
}

// ---------------------------------------------------------------------------
// Router logits + argmax (fp64): one wave per token.
// ---------------------------------------------------------------------------
__global__ __launch_bounds__(256)
void router_logits_k(const float* __restrict__ rr, const float* __restrict__ Rw2,
                     const float* __restrict__ Rb2, float* __restrict__ logits,
                     float* __restrict__ depthf) {
    const int t = blockIdx.x * 4 + (threadIdx.x >> 6);
    const int lane = threadIdx.x & 63;
    const float* xr = rr + (size_t)t * 512;
    const int c0 = lane * 4, c1 = c0 + 256;
    floatx4 a = *(const floatx4*)&xr[c0];
    floatx4 b = *(const floatx4*)&xr[c1];
    double s[4];
#pragma unroll
    for (int d = 0; d < 4; ++d) {
        const float* wr = Rw2 + d * 512;
        floatx4 wa = *(const floatx4*)&wr[c0];
        floatx4 wb = *(const floatx4*)&wr[c1];
        double acc = 0.0;
#pragma unroll
        for (int e = 0; e < 4; ++e) acc += (double)a[e] * (double)wa[e];
#pragma unroll
        for (int e = 0; e < 4; ++e) acc += (double)b[e] * (double)wb[e];
        s[d] = acc;
    }
#pragma unroll
    for (int m = 32; m >= 1; m >>= 1)
#pragma unroll
        for (int d = 0; d < 4; ++d) s[d] += __shfl_xor(s[d], m);
    if (lane == 0) {
        double bv = -1e300;
        int best = 0;
#pragma unroll
        for (int d = 0; d < 4; ++d) {
            const double v = s[d] + (double)Rb2[d];
            logits[(size_t)t * 4 + d] = (float)v;
            if (v > bv) { bv = v; best = d; }
        }
        depthf[t] = (float)(best + 1);
    }
}

// ---------------------------------------------------------------------------
// Host launcher
// ---------------------------------------------------------------------------
extern "C" void kernel_launch(void* const* d_in, const int* in_sizes, int n_in,
                              void* d_out, int out_size, void* d_ws, size_t ws_size,
                              hipStream_t stream) {
    (void)in_sizes; (void)n_in; (void)out_size; (void)ws_size;
    const float* x    = (const float*)d_in[0];
    const float* ln1g = (const float*)d_in[1];
    const float* ln1b = (const float*)d_in[2];
    const float* Wqkv = (const float*)d_in[3];
    const float* bqkv = (const float*)d_in[4];
    const float* Wo   = (const float*)d_in[5];
    const float* bo   = (const float*)d_in[6];
    const float* ln2g = (const float*)d_in[7];
    const float* ln2b = (const float*)d_in[8];
    const float* W1   = (const float*)d_in[9];
    const float* b1   = (const float*)d_in[10];
    const float* W2   = (const float*)d_in[11];
    const float* b2   = (const float*)d_in[12];
    const float* rng  = (const float*)d_in[13];
    const float* rnb  = (const float*)d_in[14];
    const float* Rw1  = (const float*)d_in[15];
    const float* Rb1  = (const float*)d_in[16];
    const float* Rw2  = (const float*)d_in[17];
    const float* Rb2  = (const float*)d_in[18];

    float* cur    = (float*)d_out;                 // (B,L,D) output, used as cur
    float* depthf = cur + (size_t)NTOK * DMODEL;   // (B,L) depths as float
    float* logits = depthf + NTOK;                 // (B,L,4)

    char* ws = (char*)d_ws;
    float* xmid = (float*)ws;                       // 16 MB f32
    u16* sbuf   = (u16*)(ws + 16777216);            //  8 MB bf16 (h / attn / h2)
    u16* qkvb   = (u16*)(ws + 25165824);            // 24 MB bf16
    u16* ffb    = (u16*)(ws + 50331648);            // 32 MB bf16
    u16* wbf    = (u16*)(ws + 83886080);            //  6 MB bf16 weights
    float* rrf  = (float*)ffb;                      // router temp (16 MB, pre-level)

    u16* wq = wbf;
    u16* wo = wbf + 786432;
    u16* w1 = wbf + 1048576;
    u16* w2 = wbf + 2097152;

    // weights -> bf16, cur = x
    cvt_w<<<12288, 256, 0, stream>>>(Wqkv, Wo, W1, W2, wbf);
    copy_f32<<<4096, 256, 0, stream>>>(x, cur);

    // router (fp64 accumulation throughout for argmax stability)
    ln_k<true><<<2048, 256, 0, stream>>>(x, rng, rnb, xmid);
    router_gemm1<<<dim3(128, 8), 256, 0, stream>>>(xmid, Rw1, Rb1, rrf);
    router_logits_k<<<2048, 256, 0, stream>>>(rrf, Rw2, Rb2, logits, depthf);

    // 4 recursion levels
    for (int level = 1; level <= 4; ++level) {
        ln_k<false><<<2048, 256, 0, stream>>>(cur, ln1g, ln1b, sbuf);
        gemm_bt<0, 128><<<dim3(64, 12), 256, 0, stream>>>(
            sbuf, wq, bqkv, qkvb, nullptr, nullptr, nullptr, 0.f, 1536, 512);
        attn_k<<<dim3(16, 32), 256, 0, stream>>>(qkvb, sbuf);
        gemm_bt<2, 64><<<dim3(64, 8), 256, 0, stream>>>(
            sbuf, wo, bo, nullptr, xmid, cur, nullptr, 0.f, 512, 512);
        ln_k<false><<<2048, 256, 0, stream>>>(xmid, ln2g, ln2b, sbuf);
        gemm_bt<1, 128><<<dim3(64, 16), 256, 0, stream>>>(
            sbuf, w1, b1, ffb, nullptr, nullptr, nullptr, 0.f, 2048, 512);
        gemm_bt<3, 64><<<dim3(64, 8), 256, 0, stream>>>(
            ffb, w2, b2, nullptr, cur, xmid, depthf, (float)level, 512, 2048);
    }
}

// Round 3
// 1133.319 us; speedup vs baseline: 1.1745x; 1.1745x over previous
//
#include <hip/hip_runtime.h>

typedef unsigned short u16;
typedef __attribute__((ext_vector_type(8))) short short8;
typedef __attribute__((ext_vector_type(4))) short s16x4;
typedef __attribute__((ext_vector_type(4))) float floatx4;
typedef __attribute__((ext_vector_type(4))) unsigned short u16x4;

#define NTOK 8192
#define DMODEL 512
#define DFF 2048
#define LSEQ 2048

__device__ __forceinline__ u16 f2bf(float f) {
    union { float f; unsigned u; } x; x.f = f;
    unsigned r = (x.u + 0x7fffu + ((x.u >> 16) & 1u)) >> 16;
    return (u16)r;
}

__device__ __forceinline__ float geluf(float x) {
    return 0.5f * x * (1.0f + erff(x * 0.70710678118654752f));
}

__device__ __forceinline__ void gload_lds16(const void* g, void* l) {
    __builtin_amdgcn_global_load_lds(
        (const __attribute__((address_space(1))) void*)g,
        (__attribute__((address_space(3))) void*)l,
        16, 0, 0);
}

// pack 4 f32 -> 4 bf16 (truncation; fine for P in [0,16])
__device__ __forceinline__ s16x4 pack_p(float p0, float p1, float p2, float p3) {
    union { float f; unsigned u; } a{p0}, b{p1}, c{p2}, d{p3};
    union { unsigned u[2]; s16x4 s; } r;
    r.u[0] = (a.u >> 16) | (b.u & 0xffff0000u);
    r.u[1] = (c.u >> 16) | (d.u & 0xffff0000u);
    return r.s;
}

// ---------------------------------------------------------------------------
// Weight f32 -> bf16 conversion (Wqkv | Wo | W1 | W2 packed)
// ---------------------------------------------------------------------------
__global__ __launch_bounds__(256) void cvt_w(const float* __restrict__ wq,
                                             const float* __restrict__ wo,
                                             const float* __restrict__ w1,
                                             const float* __restrict__ w2,
                                             u16* __restrict__ out) {
    int i = blockIdx.x * 256 + threadIdx.x;
    float v;
    if (i < 786432)       v = wq[i];
    else if (i < 1048576) v = wo[i - 786432];
    else if (i < 2097152) v = w1[i - 1048576];
    else                  v = w2[i - 2097152];
    out[i] = f2bf(v);
}

__global__ __launch_bounds__(256) void copy_f32(const float* __restrict__ a,
                                                float* __restrict__ b) {
    size_t i = ((size_t)blockIdx.x * 256 + threadIdx.x) * 4;
    *(floatx4*)&b[i] = *(const floatx4*)&a[i];
}

// ---------------------------------------------------------------------------
// LayerNorm over D=512, one wave per row.
// ---------------------------------------------------------------------------
template<bool OUTF32>
__global__ __launch_bounds__(256)
void ln_k(const float* __restrict__ x, const float* __restrict__ g,
          const float* __restrict__ bb, void* __restrict__ outp) {
    const int row = blockIdx.x * 4 + (threadIdx.x >> 6);
    const int lane = threadIdx.x & 63;
    const float* xr = x + (size_t)row * DMODEL;
    const int c0 = lane * 4, c1 = c0 + 256;
    floatx4 a = *(const floatx4*)&xr[c0];
    floatx4 b = *(const floatx4*)&xr[c1];
    float s = 0.f, sq = 0.f;
#pragma unroll
    for (int e = 0; e < 4; ++e) { s += a[e]; sq += a[e] * a[e]; }
#pragma unroll
    for (int e = 0; e < 4; ++e) { s += b[e]; sq += b[e] * b[e]; }
#pragma unroll
    for (int m = 32; m >= 1; m >>= 1) {
        s += __shfl_xor(s, m);
        sq += __shfl_xor(sq, m);
    }
    const float mean = s * (1.f / 512.f);
    const float rstd = rsqrtf(sq * (1.f / 512.f) - mean * mean + 1e-5f);
    floatx4 g0 = *(const floatx4*)&g[c0];
    floatx4 g1 = *(const floatx4*)&g[c1];
    floatx4 b0 = *(const floatx4*)&bb[c0];
    floatx4 b1 = *(const floatx4*)&bb[c1];
    floatx4 y0, y1;
#pragma unroll
    for (int e = 0; e < 4; ++e) {
        y0[e] = (a[e] - mean) * rstd * g0[e] + b0[e];
        y1[e] = (b[e] - mean) * rstd * g1[e] + b1[e];
    }
    if (OUTF32) {
        float* o = (float*)outp + (size_t)row * DMODEL;
        *(floatx4*)&o[c0] = y0;
        *(floatx4*)&o[c1] = y1;
    } else {
        u16* o = (u16*)outp + (size_t)row * DMODEL;
        u16x4 p0, p1;
#pragma unroll
        for (int e = 0; e < 4; ++e) { p0[e] = f2bf(y0[e]); p1[e] = f2bf(y1[e]); }
        *(u16x4*)&o[c0] = p0;
        *(u16x4*)&o[c1] = p1;
    }
}

// ---------------------------------------------------------------------------
// bf16 MFMA GEMM: C[M,N] = epi(A[M,K] @ Bw[N,K]^T + bias)
// EPI: 0 = bf16 out, cols<512 scaled by aux (QKV: fold softmax scale into Q)
//      1 = bf16 gelu out
//      2 = f32 out = res + v
//      3 = f32 out = keep ? res + v : old   (keep = depth[row] >= aux)
// ---------------------------------------------------------------------------
template<int EPI, int BN>
__global__ __launch_bounds__(256, 2)
void gemm_bt(const u16* __restrict__ A, const u16* __restrict__ Bw,
             const float* __restrict__ bias,
             u16* __restrict__ Cb, float* __restrict__ Cf,
             const float* __restrict__ res, const float* __restrict__ depth,
             float aux, int N, int K) {
    constexpr int NJ = BN / 32;
    __shared__ __align__(16) u16 As[128 * 32];
    __shared__ __align__(16) u16 Bs[BN * 32];
    const int tid = threadIdx.x;
    const int lane = tid & 63;
    const int w = tid >> 6;
    const int wm = (w >> 1) * 64;
    const int wn = (w & 1) * (BN / 2);
    const int mBase = blockIdx.x * 128;
    const int nBase = blockIdx.y * BN;
    const int q4 = lane >> 4, rl = lane & 15;

    floatx4 acc[4][NJ];
#pragma unroll
    for (int i = 0; i < 4; ++i)
#pragma unroll
        for (int j = 0; j < NJ; ++j) acc[i][j] = (floatx4){0.f, 0.f, 0.f, 0.f};

    const int i0 = tid, i1 = tid + 256;
    const int ar0 = i0 >> 2, ac0 = ((i0 & 3) ^ ((i0 >> 3) & 3)) * 8;
    const int ar1 = i1 >> 2, ac1 = ((i1 & 3) ^ ((i1 >> 3) & 3)) * 8;
    const u16* pA0 = A + (size_t)(mBase + ar0) * K + ac0;
    const u16* pA1 = A + (size_t)(mBase + ar1) * K + ac1;
    const u16* pB0 = Bw + (size_t)(nBase + ar0) * K + ac0;
    const u16* pB1 = (BN == 128) ? Bw + (size_t)(nBase + ar1) * K + ac1 : pB0;
    u16* lA0 = &As[i0 * 8];
    u16* lA1 = &As[i1 * 8];
    u16* lB0 = &Bs[i0 * 8];
    u16* lB1 = (BN == 128) ? &Bs[i1 * 8] : lB0;

    for (int k0 = 0; k0 < K; k0 += 32) {
        gload_lds16(pA0, lA0);
        gload_lds16(pA1, lA1);
        gload_lds16(pB0, lB0);
        if (BN == 128) gload_lds16(pB1, lB1);
        pA0 += 32; pA1 += 32; pB0 += 32;
        if (BN == 128) pB1 += 32;
        __syncthreads();
        short8 af[4], bf[NJ];
#pragma unroll
        for (int t = 0; t < 4; ++t) {
            const int r = wm + t * 16 + rl;
            af[t] = *(const short8*)&As[r * 32 + (q4 ^ ((r >> 1) & 3)) * 8];
        }
#pragma unroll
        for (int t = 0; t < NJ; ++t) {
            const int r = wn + t * 16 + rl;
            bf[t] = *(const short8*)&Bs[r * 32 + (q4 ^ ((r >> 1) & 3)) * 8];
        }
#pragma unroll
        for (int ti = 0; ti < 4; ++ti)
#pragma unroll
            for (int tj = 0; tj < NJ; ++tj)
                acc[ti][tj] = __builtin_amdgcn_mfma_f32_16x16x32_bf16(
                    af[ti], bf[tj], acc[ti][tj], 0, 0, 0);
        __syncthreads();
    }

#pragma unroll
    for (int ti = 0; ti < 4; ++ti) {
        const int r0 = mBase + wm + ti * 16 + q4 * 4;
#pragma unroll
        for (int tj = 0; tj < NJ; ++tj) {
            const int c = nBase + wn + tj * 16 + rl;
            const float bv = bias[c];
#pragma unroll
            for (int rr = 0; rr < 4; ++rr) {
                const int r = r0 + rr;
                float v = acc[ti][tj][rr] + bv;
                if (EPI == 0) {
                    if (c < 512) v *= aux;
                    Cb[(size_t)r * N + c] = f2bf(v);
                } else if (EPI == 1) {
                    Cb[(size_t)r * N + c] = f2bf(geluf(v));
                } else if (EPI == 2) {
                    Cf[(size_t)r * N + c] = res[(size_t)r * N + c] + v;
                } else {
                    if (depth[r] >= aux)
                        Cf[(size_t)r * N + c] = res[(size_t)r * N + c] + v;
                }
            }
        }
    }
}

// ---------------------------------------------------------------------------
// Flash attention via S^T: per wave 32 q-rows. S^T = K·Q^T so that the
// C-layout of P^T is directly the B-operand of mfma_16x16x16 (no P LDS
// round-trip). No max-subtraction (scores tiny; softmax shift-invariant).
// Q pre-scaled by 0.125*log2(e) in the QKV GEMM epilogue.
// ---------------------------------------------------------------------------
__global__ __launch_bounds__(256, 2)
void attn_k(const u16* __restrict__ qkv, u16* __restrict__ o) {
    const int qt = blockIdx.x;
    const int bh = blockIdx.y;
    const int b = bh >> 3, h = bh & 7;
    const int tid = threadIdx.x, lane = tid & 63, w = tid >> 6;
    const int tok0 = b * LSEQ;
    const int qrow0 = qt * 128 + w * 32;
    const int q4 = lane >> 4, rl = lane & 15;

    __shared__ __align__(16) u16 Kt[128 * 64];   // [kv][dh], chunk-swizzled
    __shared__ __align__(16) u16 Vt[64 * 132];   // [dh][kv], stride 132

    short8 qf[2][2];  // [nt][ks]  B-frag: n=q (lane rl), k=dh
#pragma unroll
    for (int nt = 0; nt < 2; ++nt)
#pragma unroll
        for (int ks = 0; ks < 2; ++ks)
            qf[nt][ks] = *(const short8*)&qkv[(size_t)(tok0 + qrow0 + nt * 16 + rl) * 1536
                                              + h * 64 + ks * 32 + q4 * 8];

    floatx4 oacc[4][2];  // [dt][nt]: O^T tile, m=dh, n=q
#pragma unroll
    for (int dt = 0; dt < 4; ++dt)
#pragma unroll
        for (int nt = 0; nt < 2; ++nt) oacc[dt][nt] = (floatx4){0.f, 0.f, 0.f, 0.f};
    float lsum[2] = {0.f, 0.f};

    for (int kt = 0; kt < 16; ++kt) {
        const int kv0 = kt * 128;
        __syncthreads();
        // stage K [128][64], 8B-chunk swizzle: slot = chunk ^ (row&7)
#pragma unroll
        for (int it = 0; it < 4; ++it) {
            const int i = it * 256 + tid;
            const int r = i >> 3;
            const int c = ((i & 7) ^ (r & 7)) * 8;
            gload_lds16(&qkv[(size_t)(tok0 + kv0 + r) * 1536 + 512 + h * 64 + c],
                        &Kt[i * 8]);
        }
        // stage V transposed: Vt[dh][kv], stride 132
        {
            const int c = tid & 63;
            const int r0 = (tid >> 6) * 4;
#pragma unroll
            for (int it = 0; it < 8; ++it) {
                const int r = r0 + it * 16;
                const u16* vp = &qkv[(size_t)(tok0 + kv0 + r) * 1536 + 1024 + h * 64 + c];
                u16x4 pk;
                pk[0] = vp[0]; pk[1] = vp[1536]; pk[2] = vp[3072]; pk[3] = vp[4608];
                *(u16x4*)&Vt[c * 132 + r] = pk;
            }
        }
        __syncthreads();

#pragma unroll
        for (int mt = 0; mt < 8; ++mt) {
            // S^T tile: A = K-frag (m=kv row rl), B = Q-frag
            const int r = mt * 16 + rl;
            short8 kf0 = *(const short8*)&Kt[r * 64 + ((q4) ^ (r & 7)) * 8];
            short8 kf1 = *(const short8*)&Kt[r * 64 + ((4 + q4) ^ (r & 7)) * 8];
            floatx4 s[2];
#pragma unroll
            for (int nt = 0; nt < 2; ++nt) {
                s[nt] = __builtin_amdgcn_mfma_f32_16x16x32_bf16(kf0, qf[nt][0],
                        (floatx4){0.f, 0.f, 0.f, 0.f}, 0, 0, 0);
                s[nt] = __builtin_amdgcn_mfma_f32_16x16x32_bf16(kf1, qf[nt][1],
                        s[nt], 0, 0, 0);
            }
            // exp2 (Q pre-scaled), pack P^T regs = B-frag of 16x16x16
            s16x4 pb[2];
#pragma unroll
            for (int nt = 0; nt < 2; ++nt) {
                const float p0 = exp2f(s[nt][0]);
                const float p1 = exp2f(s[nt][1]);
                const float p2 = exp2f(s[nt][2]);
                const float p3 = exp2f(s[nt][3]);
                lsum[nt] += (p0 + p1) + (p2 + p3);
                pb[nt] = pack_p(p0, p1, p2, p3);
            }
            // O^T += V^T-frag · P^T-frag  (A: m=dh row rl, k=kv=q4*4+j)
#pragma unroll
            for (int dt = 0; dt < 4; ++dt) {
                s16x4 vf = *(const s16x4*)&Vt[(dt * 16 + rl) * 132 + mt * 16 + q4 * 4];
#pragma unroll
                for (int nt = 0; nt < 2; ++nt)
                    oacc[dt][nt] = __builtin_amdgcn_mfma_f32_16x16x16bf16_1k(
                        vf, pb[nt], oacc[dt][nt], 0, 0, 0);
            }
        }
    }

    // finish l: reduce over q4 lanes (bits 4-5), then write O^T normalized
#pragma unroll
    for (int nt = 0; nt < 2; ++nt) {
        float l = lsum[nt];
        l += __shfl_xor(l, 16);
        l += __shfl_xor(l, 32);
        const float inv = 1.0f / l;
        const size_t row = tok0 + qrow0 + nt * 16 + rl;
#pragma unroll
        for (int dt = 0; dt < 4; ++dt) {
            u16x4 pk;
#pragma unroll
            for (int rr = 0; rr < 4; ++rr) pk[rr] = f2bf(oacc[dt][nt][rr] * inv);
            *(u16x4*)&o[row * DMODEL + h * 64 + dt * 16 + q4 * 4] = pk;
        }
    }
}

// ---------------------------------------------------------------------------
// Router GEMM1 (fp64): rr = gelu(rh @ Rw1^T + Rb1). k-major LDS tiles
// (stride 67 doubles = 134 dw ≡ 6 mod 32): broadcast A reads, 2-way writes.
// ---------------------------------------------------------------------------
__global__ __launch_bounds__(256)
void router_gemm1(const float* __restrict__ A, const float* __restrict__ W,
                  const float* __restrict__ bias, float* __restrict__ out) {
    __shared__ double At[32][67];
    __shared__ double Bt[32][67];
    const int tid = threadIdx.x;
    const int tx = tid & 15, ty = tid >> 4;
    const int mb = blockIdx.x * 64, nb = blockIdx.y * 64;
    double acc[4][4] = {};
    for (int k0 = 0; k0 < 512; k0 += 32) {
#pragma unroll
        for (int i = 0; i < 8; ++i) {
            const int e = tid + i * 256;
            const int r = e >> 5, c = e & 31;
            At[c][r] = (double)A[(size_t)(mb + r) * 512 + k0 + c];
            Bt[c][r] = (double)W[(size_t)(nb + r) * 512 + k0 + c];
        }
        __syncthreads();
#pragma unroll 4
        for (int kk = 0; kk < 32; ++kk) {
            double av[4], bv[4];
#pragma unroll
            for (int i = 0; i < 4; ++i) av[i] = At[kk][ty * 4 + i];
#pragma unroll
            for (int j = 0; j < 4; ++j) bv[j] = Bt[kk][tx * 4 + j];
#pragma unroll
            for (int i = 0; i < 4; ++i)
#pragma unroll
                for (int j = 0; j < 4; ++j)
                    acc[i][j] = fma(av[i], bv[j], acc[i][j]);
        }
        __syncthreads();
    }
#pragma unroll
    for (int i = 0; i < 4; ++i) {
        const int r = mb + ty * 4 + i;
#pragma unroll
        for (int j = 0; j < 4; ++j) {
            const int c = nb + tx * 4 + j;
            out[(size_t)r * 512 + c] = geluf((float)(acc[i][j] + (double)bias[c]));
        }
    }
}

// ---------------------------------------------------------------------------
// Router logits + argmax (fp64): one wave per token.
// ---------------------------------------------------------------------------
__global__ __launch_bounds__(256)
void router_logits_k(const float* __restrict__ rr, const float* __restrict__ Rw2,
                     const float* __restrict__ Rb2, float* __restrict__ logits,
                     float* __restrict__ depthf) {
    const int t = blockIdx.x * 4 + (threadIdx.x >> 6);
    const int lane = threadIdx.x & 63;
    const float* xr = rr + (size_t)t * 512;
    const int c0 = lane * 4, c1 = c0 + 256;
    floatx4 a = *(const floatx4*)&xr[c0];
    floatx4 b = *(const floatx4*)&xr[c1];
    double s[4];
#pragma unroll
    for (int d = 0; d < 4; ++d) {
        const float* wr = Rw2 + d * 512;
        floatx4 wa = *(const floatx4*)&wr[c0];
        floatx4 wb = *(const floatx4*)&wr[c1];
        double acc = 0.0;
#pragma unroll
        for (int e = 0; e < 4; ++e) acc += (double)a[e] * (double)wa[e];
#pragma unroll
        for (int e = 0; e < 4; ++e) acc += (double)b[e] * (double)wb[e];
        s[d] = acc;
    }
#pragma unroll
    for (int m = 32; m >= 1; m >>= 1)
#pragma unroll
        for (int d = 0; d < 4; ++d) s[d] += __shfl_xor(s[d], m);
    if (lane == 0) {
        double bv = -1e300;
        int best = 0;
#pragma unroll
        for (int d = 0; d < 4; ++d) {
            const double v = s[d] + (double)Rb2[d];
            logits[(size_t)t * 4 + d] = (float)v;
            if (v > bv) { bv = v; best = d; }
        }
        depthf[t] = (float)(best + 1);
    }
}

// ---------------------------------------------------------------------------
// Host launcher
// ---------------------------------------------------------------------------
extern "C" void kernel_launch(void* const* d_in, const int* in_sizes, int n_in,
                              void* d_out, int out_size, void* d_ws, size_t ws_size,
                              hipStream_t stream) {
    (void)in_sizes; (void)n_in; (void)out_size; (void)ws_size;
    const float* x    = (const float*)d_in[0];
    const float* ln1g = (const float*)d_in[1];
    const float* ln1b = (const float*)d_in[2];
    const float* Wqkv = (const float*)d_in[3];
    const float* bqkv = (const float*)d_in[4];
    const float* Wo   = (const float*)d_in[5];
    const float* bo   = (const float*)d_in[6];
    const float* ln2g = (const float*)d_in[7];
    const float* ln2b = (const float*)d_in[8];
    const float* W1   = (const float*)d_in[9];
    const float* b1   = (const float*)d_in[10];
    const float* W2   = (const float*)d_in[11];
    const float* b2   = (const float*)d_in[12];
    const float* rng  = (const float*)d_in[13];
    const float* rnb  = (const float*)d_in[14];
    const float* Rw1  = (const float*)d_in[15];
    const float* Rb1  = (const float*)d_in[16];
    const float* Rw2  = (const float*)d_in[17];
    const float* Rb2  = (const float*)d_in[18];

    float* cur    = (float*)d_out;
    float* depthf = cur + (size_t)NTOK * DMODEL;
    float* logits = depthf + NTOK;

    char* ws = (char*)d_ws;
    float* xmid = (float*)ws;                       // 16 MB f32
    u16* sbuf   = (u16*)(ws + 16777216);            //  8 MB bf16
    u16* qkvb   = (u16*)(ws + 25165824);            // 24 MB bf16
    u16* ffb    = (u16*)(ws + 50331648);            // 32 MB bf16
    u16* wbf    = (u16*)(ws + 83886080);            //  6 MB bf16 weights
    float* rrf  = (float*)ffb;                      // router temp (pre-level)

    u16* wq = wbf;
    u16* wo = wbf + 786432;
    u16* w1 = wbf + 1048576;
    u16* w2 = wbf + 2097152;

    const float qsc = 0.125f * 1.4426950408889634f;  // (1/sqrt(dh)) * log2(e)

    cvt_w<<<12288, 256, 0, stream>>>(Wqkv, Wo, W1, W2, wbf);
    copy_f32<<<4096, 256, 0, stream>>>(x, cur);

    ln_k<true><<<2048, 256, 0, stream>>>(x, rng, rnb, xmid);
    router_gemm1<<<dim3(128, 8), 256, 0, stream>>>(xmid, Rw1, Rb1, rrf);
    router_logits_k<<<2048, 256, 0, stream>>>(rrf, Rw2, Rb2, logits, depthf);

    for (int level = 1; level <= 4; ++level) {
        ln_k<false><<<2048, 256, 0, stream>>>(cur, ln1g, ln1b, sbuf);
        gemm_bt<0, 128><<<dim3(64, 12), 256, 0, stream>>>(
            sbuf, wq, bqkv, qkvb, nullptr, nullptr, nullptr, qsc, 1536, 512);
        attn_k<<<dim3(16, 32), 256, 0, stream>>>(qkvb, sbuf);
        gemm_bt<2, 64><<<dim3(64, 8), 256, 0, stream>>>(
            sbuf, wo, bo, nullptr, xmid, cur, nullptr, 0.f, 512, 512);
        ln_k<false><<<2048, 256, 0, stream>>>(xmid, ln2g, ln2b, sbuf);
        gemm_bt<1, 128><<<dim3(64, 16), 256, 0, stream>>>(
            sbuf, w1, b1, ffb, nullptr, nullptr, nullptr, 0.f, 2048, 512);
        gemm_bt<3, 64><<<dim3(64, 8), 256, 0, stream>>>(
            ffb, w2, b2, nullptr, cur, xmid, depthf, (float)level, 512, 2048);
    }
}

// Round 4
// 1046.470 us; speedup vs baseline: 1.2720x; 1.0830x over previous
//
#include <hip/hip_runtime.h>

typedef unsigned short u16;
typedef __attribute__((ext_vector_type(8))) short short8;
typedef __attribute__((ext_vector_type(4))) short s16x4;
typedef __attribute__((ext_vector_type(4))) float floatx4;
typedef __attribute__((ext_vector_type(4))) unsigned short u16x4;

#define NTOK 8192
#define DMODEL 512
#define DFF 2048
#define LSEQ 2048

__device__ __forceinline__ u16 f2bf(float f) {
    union { float f; unsigned u; } x; x.f = f;
    unsigned r = (x.u + 0x7fffu + ((x.u >> 16) & 1u)) >> 16;
    return (u16)r;
}

__device__ __forceinline__ float geluf(float x) {
    return 0.5f * x * (1.0f + erff(x * 0.70710678118654752f));
}

__device__ __forceinline__ void gload_lds16(const void* g, void* l) {
    __builtin_amdgcn_global_load_lds(
        (const __attribute__((address_space(1))) void*)g,
        (__attribute__((address_space(3))) void*)l,
        16, 0, 0);
}

// pack 4 f32 -> 4 bf16 (truncation; fine for P in [0,16])
__device__ __forceinline__ s16x4 pack_p(float p0, float p1, float p2, float p3) {
    union { float f; unsigned u; } a{p0}, b{p1}, c{p2}, d{p3};
    union { unsigned u[2]; s16x4 s; } r;
    r.u[0] = (a.u >> 16) | (b.u & 0xffff0000u);
    r.u[1] = (c.u >> 16) | (d.u & 0xffff0000u);
    return r.s;
}

// ---------------------------------------------------------------------------
// Weight f32 -> bf16 conversion (Wqkv | Wo | W1 | W2 packed)
// ---------------------------------------------------------------------------
__global__ __launch_bounds__(256) void cvt_w(const float* __restrict__ wq,
                                             const float* __restrict__ wo,
                                             const float* __restrict__ w1,
                                             const float* __restrict__ w2,
                                             u16* __restrict__ out) {
    int i = blockIdx.x * 256 + threadIdx.x;
    float v;
    if (i < 786432)       v = wq[i];
    else if (i < 1048576) v = wo[i - 786432];
    else if (i < 2097152) v = w1[i - 1048576];
    else                  v = w2[i - 2097152];
    out[i] = f2bf(v);
}

__global__ __launch_bounds__(256) void copy_f32(const float* __restrict__ a,
                                                float* __restrict__ b) {
    size_t i = ((size_t)blockIdx.x * 256 + threadIdx.x) * 4;
    *(floatx4*)&b[i] = *(const floatx4*)&a[i];
}

// ---------------------------------------------------------------------------
// LayerNorm over D=512, one wave per row.
// ---------------------------------------------------------------------------
template<bool OUTF32>
__global__ __launch_bounds__(256)
void ln_k(const float* __restrict__ x, const float* __restrict__ g,
          const float* __restrict__ bb, void* __restrict__ outp) {
    const int row = blockIdx.x * 4 + (threadIdx.x >> 6);
    const int lane = threadIdx.x & 63;
    const float* xr = x + (size_t)row * DMODEL;
    const int c0 = lane * 4, c1 = c0 + 256;
    floatx4 a = *(const floatx4*)&xr[c0];
    floatx4 b = *(const floatx4*)&xr[c1];
    float s = 0.f, sq = 0.f;
#pragma unroll
    for (int e = 0; e < 4; ++e) { s += a[e]; sq += a[e] * a[e]; }
#pragma unroll
    for (int e = 0; e < 4; ++e) { s += b[e]; sq += b[e] * b[e]; }
#pragma unroll
    for (int m = 32; m >= 1; m >>= 1) {
        s += __shfl_xor(s, m);
        sq += __shfl_xor(sq, m);
    }
    const float mean = s * (1.f / 512.f);
    const float rstd = rsqrtf(sq * (1.f / 512.f) - mean * mean + 1e-5f);
    floatx4 g0 = *(const floatx4*)&g[c0];
    floatx4 g1 = *(const floatx4*)&g[c1];
    floatx4 b0 = *(const floatx4*)&bb[c0];
    floatx4 b1 = *(const floatx4*)&bb[c1];
    floatx4 y0, y1;
#pragma unroll
    for (int e = 0; e < 4; ++e) {
        y0[e] = (a[e] - mean) * rstd * g0[e] + b0[e];
        y1[e] = (b[e] - mean) * rstd * g1[e] + b1[e];
    }
    if (OUTF32) {
        float* o = (float*)outp + (size_t)row * DMODEL;
        *(floatx4*)&o[c0] = y0;
        *(floatx4*)&o[c1] = y1;
    } else {
        u16* o = (u16*)outp + (size_t)row * DMODEL;
        u16x4 p0, p1;
#pragma unroll
        for (int e = 0; e < 4; ++e) { p0[e] = f2bf(y0[e]); p1[e] = f2bf(y1[e]); }
        *(u16x4*)&o[c0] = p0;
        *(u16x4*)&o[c1] = p1;
    }
}

// ---------------------------------------------------------------------------
// bf16 MFMA GEMM: C[M,N] = epi(A[M,K] @ Bw[N,K]^T + bias)
// EPI: 0 = bf16 out, cols<512 scaled by aux (QKV: fold softmax scale into Q)
//      1 = bf16 gelu out
//      2 = f32 out = res + v
//      3 = f32 out = keep ? res + v : old   (keep = depth[row] >= aux)
// ---------------------------------------------------------------------------
template<int EPI, int BN>
__global__ __launch_bounds__(256, 2)
void gemm_bt(const u16* __restrict__ A, const u16* __restrict__ Bw,
             const float* __restrict__ bias,
             u16* __restrict__ Cb, float* __restrict__ Cf,
             const float* __restrict__ res, const float* __restrict__ depth,
             float aux, int N, int K) {
    constexpr int NJ = BN / 32;
    __shared__ __align__(16) u16 As[128 * 32];
    __shared__ __align__(16) u16 Bs[BN * 32];
    const int tid = threadIdx.x;
    const int lane = tid & 63;
    const int w = tid >> 6;
    const int wm = (w >> 1) * 64;
    const int wn = (w & 1) * (BN / 2);
    const int mBase = blockIdx.x * 128;
    const int nBase = blockIdx.y * BN;
    const int q4 = lane >> 4, rl = lane & 15;

    floatx4 acc[4][NJ];
#pragma unroll
    for (int i = 0; i < 4; ++i)
#pragma unroll
        for (int j = 0; j < NJ; ++j) acc[i][j] = (floatx4){0.f, 0.f, 0.f, 0.f};

    const int i0 = tid, i1 = tid + 256;
    const int ar0 = i0 >> 2, ac0 = ((i0 & 3) ^ ((i0 >> 3) & 3)) * 8;
    const int ar1 = i1 >> 2, ac1 = ((i1 & 3) ^ ((i1 >> 3) & 3)) * 8;
    const u16* pA0 = A + (size_t)(mBase + ar0) * K + ac0;
    const u16* pA1 = A + (size_t)(mBase + ar1) * K + ac1;
    const u16* pB0 = Bw + (size_t)(nBase + ar0) * K + ac0;
    const u16* pB1 = (BN == 128) ? Bw + (size_t)(nBase + ar1) * K + ac1 : pB0;
    u16* lA0 = &As[i0 * 8];
    u16* lA1 = &As[i1 * 8];
    u16* lB0 = &Bs[i0 * 8];
    u16* lB1 = (BN == 128) ? &Bs[i1 * 8] : lB0;

    for (int k0 = 0; k0 < K; k0 += 32) {
        gload_lds16(pA0, lA0);
        gload_lds16(pA1, lA1);
        gload_lds16(pB0, lB0);
        if (BN == 128) gload_lds16(pB1, lB1);
        pA0 += 32; pA1 += 32; pB0 += 32;
        if (BN == 128) pB1 += 32;
        __syncthreads();
        short8 af[4], bf[NJ];
#pragma unroll
        for (int t = 0; t < 4; ++t) {
            const int r = wm + t * 16 + rl;
            af[t] = *(const short8*)&As[r * 32 + (q4 ^ ((r >> 1) & 3)) * 8];
        }
#pragma unroll
        for (int t = 0; t < NJ; ++t) {
            const int r = wn + t * 16 + rl;
            bf[t] = *(const short8*)&Bs[r * 32 + (q4 ^ ((r >> 1) & 3)) * 8];
        }
#pragma unroll
        for (int ti = 0; ti < 4; ++ti)
#pragma unroll
            for (int tj = 0; tj < NJ; ++tj)
                acc[ti][tj] = __builtin_amdgcn_mfma_f32_16x16x32_bf16(
                    af[ti], bf[tj], acc[ti][tj], 0, 0, 0);
        __syncthreads();
    }

#pragma unroll
    for (int ti = 0; ti < 4; ++ti) {
        const int r0 = mBase + wm + ti * 16 + q4 * 4;
#pragma unroll
        for (int tj = 0; tj < NJ; ++tj) {
            const int c = nBase + wn + tj * 16 + rl;
            const float bv = bias[c];
#pragma unroll
            for (int rr = 0; rr < 4; ++rr) {
                const int r = r0 + rr;
                float v = acc[ti][tj][rr] + bv;
                if (EPI == 0) {
                    if (c < 512) v *= aux;
                    Cb[(size_t)r * N + c] = f2bf(v);
                } else if (EPI == 1) {
                    Cb[(size_t)r * N + c] = f2bf(geluf(v));
                } else if (EPI == 2) {
                    Cf[(size_t)r * N + c] = res[(size_t)r * N + c] + v;
                } else {
                    if (depth[r] >= aux)
                        Cf[(size_t)r * N + c] = res[(size_t)r * N + c] + v;
                }
            }
        }
    }
}

// ---------------------------------------------------------------------------
// Flash attention via S^T (register-resident P^T). See R3 notes.
// ---------------------------------------------------------------------------
__global__ __launch_bounds__(256, 2)
void attn_k(const u16* __restrict__ qkv, u16* __restrict__ o) {
    const int qt = blockIdx.x;
    const int bh = blockIdx.y;
    const int b = bh >> 3, h = bh & 7;
    const int tid = threadIdx.x, lane = tid & 63, w = tid >> 6;
    const int tok0 = b * LSEQ;
    const int qrow0 = qt * 128 + w * 32;
    const int q4 = lane >> 4, rl = lane & 15;

    __shared__ __align__(16) u16 Kt[128 * 64];   // [kv][dh], chunk-swizzled
    __shared__ __align__(16) u16 Vt[64 * 132];   // [dh][kv], stride 132

    short8 qf[2][2];
#pragma unroll
    for (int nt = 0; nt < 2; ++nt)
#pragma unroll
        for (int ks = 0; ks < 2; ++ks)
            qf[nt][ks] = *(const short8*)&qkv[(size_t)(tok0 + qrow0 + nt * 16 + rl) * 1536
                                              + h * 64 + ks * 32 + q4 * 8];

    floatx4 oacc[4][2];
#pragma unroll
    for (int dt = 0; dt < 4; ++dt)
#pragma unroll
        for (int nt = 0; nt < 2; ++nt) oacc[dt][nt] = (floatx4){0.f, 0.f, 0.f, 0.f};
    float lsum[2] = {0.f, 0.f};

    for (int kt = 0; kt < 16; ++kt) {
        const int kv0 = kt * 128;
        __syncthreads();
#pragma unroll
        for (int it = 0; it < 4; ++it) {
            const int i = it * 256 + tid;
            const int r = i >> 3;
            const int c = ((i & 7) ^ (r & 7)) * 8;
            gload_lds16(&qkv[(size_t)(tok0 + kv0 + r) * 1536 + 512 + h * 64 + c],
                        &Kt[i * 8]);
        }
        {
            const int c = tid & 63;
            const int r0 = (tid >> 6) * 4;
#pragma unroll
            for (int it = 0; it < 8; ++it) {
                const int r = r0 + it * 16;
                const u16* vp = &qkv[(size_t)(tok0 + kv0 + r) * 1536 + 1024 + h * 64 + c];
                u16x4 pk;
                pk[0] = vp[0]; pk[1] = vp[1536]; pk[2] = vp[3072]; pk[3] = vp[4608];
                *(u16x4*)&Vt[c * 132 + r] = pk;
            }
        }
        __syncthreads();

#pragma unroll
        for (int mt = 0; mt < 8; ++mt) {
            const int r = mt * 16 + rl;
            short8 kf0 = *(const short8*)&Kt[r * 64 + ((q4) ^ (r & 7)) * 8];
            short8 kf1 = *(const short8*)&Kt[r * 64 + ((4 + q4) ^ (r & 7)) * 8];
            floatx4 s[2];
#pragma unroll
            for (int nt = 0; nt < 2; ++nt) {
                s[nt] = __builtin_amdgcn_mfma_f32_16x16x32_bf16(kf0, qf[nt][0],
                        (floatx4){0.f, 0.f, 0.f, 0.f}, 0, 0, 0);
                s[nt] = __builtin_amdgcn_mfma_f32_16x16x32_bf16(kf1, qf[nt][1],
                        s[nt], 0, 0, 0);
            }
            s16x4 pb[2];
#pragma unroll
            for (int nt = 0; nt < 2; ++nt) {
                const float p0 = exp2f(s[nt][0]);
                const float p1 = exp2f(s[nt][1]);
                const float p2 = exp2f(s[nt][2]);
                const float p3 = exp2f(s[nt][3]);
                lsum[nt] += (p0 + p1) + (p2 + p3);
                pb[nt] = pack_p(p0, p1, p2, p3);
            }
#pragma unroll
            for (int dt = 0; dt < 4; ++dt) {
                s16x4 vf = *(const s16x4*)&Vt[(dt * 16 + rl) * 132 + mt * 16 + q4 * 4];
#pragma unroll
                for (int nt = 0; nt < 2; ++nt)
                    oacc[dt][nt] = __builtin_amdgcn_mfma_f32_16x16x16bf16_1k(
                        vf, pb[nt], oacc[dt][nt], 0, 0, 0);
            }
        }
    }

#pragma unroll
    for (int nt = 0; nt < 2; ++nt) {
        float l = lsum[nt];
        l += __shfl_xor(l, 16);
        l += __shfl_xor(l, 32);
        const float inv = 1.0f / l;
        const size_t row = tok0 + qrow0 + nt * 16 + rl;
#pragma unroll
        for (int dt = 0; dt < 4; ++dt) {
            u16x4 pk;
#pragma unroll
            for (int rr = 0; rr < 4; ++rr) pk[rr] = f2bf(oacc[dt][nt][rr] * inv);
            *(u16x4*)&o[row * DMODEL + h * 64 + dt * 16 + q4 * 4] = pk;
        }
    }
}

// ---------------------------------------------------------------------------
// Router GEMM1 (fp64 accum): rr = gelu(rh @ Rw1^T + Rb1).
// f32 k-major LDS tiles, cvt to f64 in regs. 64x128 block, 4x8/thread.
// Strided column ownership (n = tx + 16j) -> conflict-free b32 B reads;
// A read = one b128 broadcast. Pads 68/132 (stride mod 32 = 4).
// ---------------------------------------------------------------------------
__global__ __launch_bounds__(256, 2)
void router_gemm1(const float* __restrict__ A, const float* __restrict__ W,
                  const float* __restrict__ bias, float* __restrict__ out) {
    __shared__ float Af[32][68];
    __shared__ float Bf[32][132];
    const int tid = threadIdx.x;
    const int tx = tid & 15, ty = tid >> 4;
    const int mb = blockIdx.x * 64, nb = blockIdx.y * 128;
    double acc[4][8] = {};
    for (int k0 = 0; k0 < 512; k0 += 32) {
        // stage A 64x32 k-major (transpose via register float4)
#pragma unroll
        for (int it = 0; it < 2; ++it) {
            const int ch = tid + it * 256;
            const int m = ch >> 3, c4 = (ch & 7) * 4;
            const floatx4 v = *(const floatx4*)&A[(size_t)(mb + m) * 512 + k0 + c4];
#pragma unroll
            for (int e = 0; e < 4; ++e) Af[c4 + e][m] = v[e];
        }
        // stage B 128x32 k-major
#pragma unroll
        for (int it = 0; it < 4; ++it) {
            const int ch = tid + it * 256;
            const int n = ch >> 3, c4 = (ch & 7) * 4;
            const floatx4 v = *(const floatx4*)&W[(size_t)(nb + n) * 512 + k0 + c4];
#pragma unroll
            for (int e = 0; e < 4; ++e) Bf[c4 + e][n] = v[e];
        }
        __syncthreads();
#pragma unroll 4
        for (int kk = 0; kk < 32; ++kk) {
            const floatx4 a4 = *(const floatx4*)&Af[kk][ty * 4];
            double av[4], bv[8];
#pragma unroll
            for (int i = 0; i < 4; ++i) av[i] = (double)a4[i];
#pragma unroll
            for (int j = 0; j < 8; ++j) bv[j] = (double)Bf[kk][tx + 16 * j];
#pragma unroll
            for (int i = 0; i < 4; ++i)
#pragma unroll
                for (int j = 0; j < 8; ++j)
                    acc[i][j] = fma(av[i], bv[j], acc[i][j]);
        }
        __syncthreads();
    }
#pragma unroll
    for (int i = 0; i < 4; ++i) {
        const int r = mb + ty * 4 + i;
#pragma unroll
        for (int j = 0; j < 8; ++j) {
            const int c = nb + tx + 16 * j;
            out[(size_t)r * 512 + c] = geluf((float)(acc[i][j] + (double)bias[c]));
        }
    }
}

// ---------------------------------------------------------------------------
// Router logits + argmax (fp64): one wave per token.
// ---------------------------------------------------------------------------
__global__ __launch_bounds__(256)
void router_logits_k(const float* __restrict__ rr, const float* __restrict__ Rw2,
                     const float* __restrict__ Rb2, float* __restrict__ logits,
                     float* __restrict__ depthf) {
    const int t = blockIdx.x * 4 + (threadIdx.x >> 6);
    const int lane = threadIdx.x & 63;
    const float* xr = rr + (size_t)t * 512;
    const int c0 = lane * 4, c1 = c0 + 256;
    floatx4 a = *(const floatx4*)&xr[c0];
    floatx4 b = *(const floatx4*)&xr[c1];
    double s[4];
#pragma unroll
    for (int d = 0; d < 4; ++d) {
        const float* wr = Rw2 + d * 512;
        floatx4 wa = *(const floatx4*)&wr[c0];
        floatx4 wb = *(const floatx4*)&wr[c1];
        double acc = 0.0;
#pragma unroll
        for (int e = 0; e < 4; ++e) acc += (double)a[e] * (double)wa[e];
#pragma unroll
        for (int e = 0; e < 4; ++e) acc += (double)b[e] * (double)wb[e];
        s[d] = acc;
    }
#pragma unroll
    for (int m = 32; m >= 1; m >>= 1)
#pragma unroll
        for (int d = 0; d < 4; ++d) s[d] += __shfl_xor(s[d], m);
    if (lane == 0) {
        double bv = -1e300;
        int best = 0;
#pragma unroll
        for (int d = 0; d < 4; ++d) {
            const double v = s[d] + (double)Rb2[d];
            logits[(size_t)t * 4 + d] = (float)v;
            if (v > bv) { bv = v; best = d; }
        }
        depthf[t] = (float)(best + 1);
    }
}

// ---------------------------------------------------------------------------
// Host launcher
// ---------------------------------------------------------------------------
extern "C" void kernel_launch(void* const* d_in, const int* in_sizes, int n_in,
                              void* d_out, int out_size, void* d_ws, size_t ws_size,
                              hipStream_t stream) {
    (void)in_sizes; (void)n_in; (void)out_size; (void)ws_size;
    const float* x    = (const float*)d_in[0];
    const float* ln1g = (const float*)d_in[1];
    const float* ln1b = (const float*)d_in[2];
    const float* Wqkv = (const float*)d_in[3];
    const float* bqkv = (const float*)d_in[4];
    const float* Wo   = (const float*)d_in[5];
    const float* bo   = (const float*)d_in[6];
    const float* ln2g = (const float*)d_in[7];
    const float* ln2b = (const float*)d_in[8];
    const float* W1   = (const float*)d_in[9];
    const float* b1   = (const float*)d_in[10];
    const float* W2   = (const float*)d_in[11];
    const float* b2   = (const float*)d_in[12];
    const float* rng  = (const float*)d_in[13];
    const float* rnb  = (const float*)d_in[14];
    const float* Rw1  = (const float*)d_in[15];
    const float* Rb1  = (const float*)d_in[16];
    const float* Rw2  = (const float*)d_in[17];
    const float* Rb2  = (const float*)d_in[18];

    float* cur    = (float*)d_out;
    float* depthf = cur + (size_t)NTOK * DMODEL;
    float* logits = depthf + NTOK;

    char* ws = (char*)d_ws;
    float* xmid = (float*)ws;                       // 16 MB f32
    u16* sbuf   = (u16*)(ws + 16777216);            //  8 MB bf16
    u16* qkvb   = (u16*)(ws + 25165824);            // 24 MB bf16
    u16* ffb    = (u16*)(ws + 50331648);            // 32 MB bf16
    u16* wbf    = (u16*)(ws + 83886080);            //  6 MB bf16 weights
    float* rrf  = (float*)ffb;                      // router temp (pre-level)

    u16* wq = wbf;
    u16* wo = wbf + 786432;
    u16* w1 = wbf + 1048576;
    u16* w2 = wbf + 2097152;

    const float qsc = 0.125f * 1.4426950408889634f;  // (1/sqrt(dh)) * log2(e)

    cvt_w<<<12288, 256, 0, stream>>>(Wqkv, Wo, W1, W2, wbf);
    copy_f32<<<4096, 256, 0, stream>>>(x, cur);

    ln_k<true><<<2048, 256, 0, stream>>>(x, rng, rnb, xmid);
    router_gemm1<<<dim3(128, 4), 256, 0, stream>>>(xmid, Rw1, Rb1, rrf);
    router_logits_k<<<2048, 256, 0, stream>>>(rrf, Rw2, Rb2, logits, depthf);

    for (int level = 1; level <= 4; ++level) {
        ln_k<false><<<2048, 256, 0, stream>>>(cur, ln1g, ln1b, sbuf);
        gemm_bt<0, 128><<<dim3(64, 12), 256, 0, stream>>>(
            sbuf, wq, bqkv, qkvb, nullptr, nullptr, nullptr, qsc, 1536, 512);
        attn_k<<<dim3(16, 32), 256, 0, stream>>>(qkvb, sbuf);
        gemm_bt<2, 64><<<dim3(64, 8), 256, 0, stream>>>(
            sbuf, wo, bo, nullptr, xmid, cur, nullptr, 0.f, 512, 512);
        ln_k<false><<<2048, 256, 0, stream>>>(xmid, ln2g, ln2b, sbuf);
        gemm_bt<1, 128><<<dim3(64, 16), 256, 0, stream>>>(
            sbuf, w1, b1, ffb, nullptr, nullptr, nullptr, 0.f, 2048, 512);
        gemm_bt<3, 64><<<dim3(64, 8), 256, 0, stream>>>(
            ffb, w2, b2, nullptr, cur, xmid, depthf, (float)level, 512, 2048);
    }
}

// Round 5
// 940.963 us; speedup vs baseline: 1.4146x; 1.1121x over previous
//
#include <hip/hip_runtime.h>

typedef unsigned short u16;
typedef __attribute__((ext_vector_type(8))) short short8;
typedef __attribute__((ext_vector_type(4))) short s16x4;
typedef __attribute__((ext_vector_type(4))) float floatx4;
typedef __attribute__((ext_vector_type(4))) unsigned short u16x4;

#define NTOK 8192
#define DMODEL 512
#define DFF 2048
#define LSEQ 2048

__device__ __forceinline__ u16 f2bf(float f) {
    union { float f; unsigned u; } x; x.f = f;
    unsigned r = (x.u + 0x7fffu + ((x.u >> 16) & 1u)) >> 16;
    return (u16)r;
}

__device__ __forceinline__ float geluf(float x) {
    return 0.5f * x * (1.0f + erff(x * 0.70710678118654752f));
}

__device__ __forceinline__ void gload_lds16(const void* g, void* l) {
    __builtin_amdgcn_global_load_lds(
        (const __attribute__((address_space(1))) void*)g,
        (__attribute__((address_space(3))) void*)l,
        16, 0, 0);
}

// pack 4 f32 -> 4 bf16 (truncation; fine for P in [0,16])
__device__ __forceinline__ s16x4 pack_p(float p0, float p1, float p2, float p3) {
    union { float f; unsigned u; } a{p0}, b{p1}, c{p2}, d{p3};
    union { unsigned u[2]; s16x4 s; } r;
    r.u[0] = (a.u >> 16) | (b.u & 0xffff0000u);
    r.u[1] = (c.u >> 16) | (d.u & 0xffff0000u);
    return r.s;
}

// ---------------------------------------------------------------------------
// Weight f32 -> bf16 conversion (Wqkv | Wo | W1 | W2 packed)
// ---------------------------------------------------------------------------
__global__ __launch_bounds__(256) void cvt_w(const float* __restrict__ wq,
                                             const float* __restrict__ wo,
                                             const float* __restrict__ w1,
                                             const float* __restrict__ w2,
                                             u16* __restrict__ out) {
    int i = blockIdx.x * 256 + threadIdx.x;
    float v;
    if (i < 786432)       v = wq[i];
    else if (i < 1048576) v = wo[i - 786432];
    else if (i < 2097152) v = w1[i - 1048576];
    else                  v = w2[i - 2097152];
    out[i] = f2bf(v);
}

__global__ __launch_bounds__(256) void copy_f32(const float* __restrict__ a,
                                                float* __restrict__ b) {
    size_t i = ((size_t)blockIdx.x * 256 + threadIdx.x) * 4;
    *(floatx4*)&b[i] = *(const floatx4*)&a[i];
}

// ---------------------------------------------------------------------------
// LayerNorm over D=512, one wave per row.
// ---------------------------------------------------------------------------
template<bool OUTF32>
__global__ __launch_bounds__(256)
void ln_k(const float* __restrict__ x, const float* __restrict__ g,
          const float* __restrict__ bb, void* __restrict__ outp) {
    const int row = blockIdx.x * 4 + (threadIdx.x >> 6);
    const int lane = threadIdx.x & 63;
    const float* xr = x + (size_t)row * DMODEL;
    const int c0 = lane * 4, c1 = c0 + 256;
    floatx4 a = *(const floatx4*)&xr[c0];
    floatx4 b = *(const floatx4*)&xr[c1];
    float s = 0.f, sq = 0.f;
#pragma unroll
    for (int e = 0; e < 4; ++e) { s += a[e]; sq += a[e] * a[e]; }
#pragma unroll
    for (int e = 0; e < 4; ++e) { s += b[e]; sq += b[e] * b[e]; }
#pragma unroll
    for (int m = 32; m >= 1; m >>= 1) {
        s += __shfl_xor(s, m);
        sq += __shfl_xor(sq, m);
    }
    const float mean = s * (1.f / 512.f);
    const float rstd = rsqrtf(sq * (1.f / 512.f) - mean * mean + 1e-5f);
    floatx4 g0 = *(const floatx4*)&g[c0];
    floatx4 g1 = *(const floatx4*)&g[c1];
    floatx4 b0 = *(const floatx4*)&bb[c0];
    floatx4 b1 = *(const floatx4*)&bb[c1];
    floatx4 y0, y1;
#pragma unroll
    for (int e = 0; e < 4; ++e) {
        y0[e] = (a[e] - mean) * rstd * g0[e] + b0[e];
        y1[e] = (b[e] - mean) * rstd * g1[e] + b1[e];
    }
    if (OUTF32) {
        float* o = (float*)outp + (size_t)row * DMODEL;
        *(floatx4*)&o[c0] = y0;
        *(floatx4*)&o[c1] = y1;
    } else {
        u16* o = (u16*)outp + (size_t)row * DMODEL;
        u16x4 p0, p1;
#pragma unroll
        for (int e = 0; e < 4; ++e) { p0[e] = f2bf(y0[e]); p1[e] = f2bf(y1[e]); }
        *(u16x4*)&o[c0] = p0;
        *(u16x4*)&o[c1] = p1;
    }
}

// ---------------------------------------------------------------------------
// bf16 MFMA GEMM: C[M,N] = epi(A[M,K] @ Bw[N,K]^T + bias)
// EPI: 0 = QKV: Q (nBase<512) scaled by aux -> qk stride 1024;
//          K (512<=nBase<1024) -> qk stride 1024;
//          V (nBase>=1024) -> Cv transposed [bh][dh][kv]
//      1 = bf16 gelu out (stride N)
//      2 = f32 out = res + v
//      3 = f32 out = keep ? res + v : old   (keep = depth[row] >= aux)
// ---------------------------------------------------------------------------
template<int EPI, int BN>
__global__ __launch_bounds__(256, 2)
void gemm_bt(const u16* __restrict__ A, const u16* __restrict__ Bw,
             const float* __restrict__ bias,
             u16* __restrict__ Cb, float* __restrict__ Cf,
             const float* __restrict__ res, const float* __restrict__ depth,
             u16* __restrict__ Cv,
             float aux, int N, int K) {
    constexpr int NJ = BN / 32;
    __shared__ __align__(16) u16 As[128 * 32];
    __shared__ __align__(16) u16 Bs[BN * 32];
    const int tid = threadIdx.x;
    const int lane = tid & 63;
    const int w = tid >> 6;
    const int wm = (w >> 1) * 64;
    const int wn = (w & 1) * (BN / 2);
    const int mBase = blockIdx.x * 128;
    const int nBase = blockIdx.y * BN;
    const int q4 = lane >> 4, rl = lane & 15;

    floatx4 acc[4][NJ];
#pragma unroll
    for (int i = 0; i < 4; ++i)
#pragma unroll
        for (int j = 0; j < NJ; ++j) acc[i][j] = (floatx4){0.f, 0.f, 0.f, 0.f};

    const int i0 = tid, i1 = tid + 256;
    const int ar0 = i0 >> 2, ac0 = ((i0 & 3) ^ ((i0 >> 3) & 3)) * 8;
    const int ar1 = i1 >> 2, ac1 = ((i1 & 3) ^ ((i1 >> 3) & 3)) * 8;
    const u16* pA0 = A + (size_t)(mBase + ar0) * K + ac0;
    const u16* pA1 = A + (size_t)(mBase + ar1) * K + ac1;
    const u16* pB0 = Bw + (size_t)(nBase + ar0) * K + ac0;
    const u16* pB1 = (BN == 128) ? Bw + (size_t)(nBase + ar1) * K + ac1 : pB0;
    u16* lA0 = &As[i0 * 8];
    u16* lA1 = &As[i1 * 8];
    u16* lB0 = &Bs[i0 * 8];
    u16* lB1 = (BN == 128) ? &Bs[i1 * 8] : lB0;

    for (int k0 = 0; k0 < K; k0 += 32) {
        gload_lds16(pA0, lA0);
        gload_lds16(pA1, lA1);
        gload_lds16(pB0, lB0);
        if (BN == 128) gload_lds16(pB1, lB1);
        pA0 += 32; pA1 += 32; pB0 += 32;
        if (BN == 128) pB1 += 32;
        __syncthreads();
        short8 af[4], bf[NJ];
#pragma unroll
        for (int t = 0; t < 4; ++t) {
            const int r = wm + t * 16 + rl;
            af[t] = *(const short8*)&As[r * 32 + (q4 ^ ((r >> 1) & 3)) * 8];
        }
#pragma unroll
        for (int t = 0; t < NJ; ++t) {
            const int r = wn + t * 16 + rl;
            bf[t] = *(const short8*)&Bs[r * 32 + (q4 ^ ((r >> 1) & 3)) * 8];
        }
#pragma unroll
        for (int ti = 0; ti < 4; ++ti)
#pragma unroll
            for (int tj = 0; tj < NJ; ++tj)
                acc[ti][tj] = __builtin_amdgcn_mfma_f32_16x16x32_bf16(
                    af[ti], bf[tj], acc[ti][tj], 0, 0, 0);
        __syncthreads();
    }

#pragma unroll
    for (int ti = 0; ti < 4; ++ti) {
        const int r0 = mBase + wm + ti * 16 + q4 * 4;
#pragma unroll
        for (int tj = 0; tj < NJ; ++tj) {
            const int c = nBase + wn + tj * 16 + rl;
            const float bv = bias[c];
            if (EPI == 0) {
                if (nBase < 1024) {
                    const float sc = (nBase < 512) ? aux : 1.0f;
#pragma unroll
                    for (int rr = 0; rr < 4; ++rr)
                        Cb[(size_t)(r0 + rr) * 1024 + c] =
                            f2bf((acc[ti][tj][rr] + bv) * sc);
                } else {
                    // V transposed: vT[((b*8+h)*64+dh)*2048 + kv]
                    const int cm = c - 1024;
                    const int hh = cm >> 6, dh = cm & 63;
                    const int bb2 = r0 >> 11, kv = r0 & 2047;
                    u16x4 pk;
#pragma unroll
                    for (int rr = 0; rr < 4; ++rr)
                        pk[rr] = f2bf(acc[ti][tj][rr] + bv);
                    *(u16x4*)&Cv[((size_t)(bb2 * 8 + hh) * 64 + dh) * 2048 + kv] = pk;
                }
            } else {
#pragma unroll
                for (int rr = 0; rr < 4; ++rr) {
                    const int r = r0 + rr;
                    const float v = acc[ti][tj][rr] + bv;
                    if (EPI == 1) {
                        Cb[(size_t)r * N + c] = f2bf(geluf(v));
                    } else if (EPI == 2) {
                        Cf[(size_t)r * N + c] = res[(size_t)r * N + c] + v;
                    } else {
                        if (depth[r] >= aux)
                            Cf[(size_t)r * N + c] = res[(size_t)r * N + c] + v;
                    }
                }
            }
        }
    }
}

// ---------------------------------------------------------------------------
// Flash attention via S^T (register-resident P^T). 64 q-rows/block (16/wave),
// grid 32x32 = 1024 blocks -> 4 blocks/CU. K and V^T both staged with
// global_load_lds width-16 + XOR chunk swizzle. V^T comes pre-transposed
// from the QKV GEMM epilogue (vT[bh][dh][kv]).
// ---------------------------------------------------------------------------
__global__ __launch_bounds__(256, 4)
void attn_k(const u16* __restrict__ qk, const u16* __restrict__ vT,
            u16* __restrict__ o) {
    const int qt = blockIdx.x;
    const int bh = blockIdx.y;
    const int b = bh >> 3, h = bh & 7;
    const int tid = threadIdx.x, lane = tid & 63, w = tid >> 6;
    const int tok0 = b * LSEQ;
    const int qrow0 = qt * 64 + w * 16;
    const int q4 = lane >> 4, rl = lane & 15;

    __shared__ __align__(16) u16 Kt[128 * 64];   // [kv][dh], chunk-swizzled
    __shared__ __align__(16) u16 Vt[64 * 128];   // [dh][kv], chunk-swizzled

    const u16* vbase = vT + (size_t)bh * 64 * 2048;

    short8 qf[2];
#pragma unroll
    for (int ks = 0; ks < 2; ++ks)
        qf[ks] = *(const short8*)&qk[(size_t)(tok0 + qrow0 + rl) * 1024
                                      + h * 64 + ks * 32 + q4 * 8];

    floatx4 oacc[4];
#pragma unroll
    for (int dt = 0; dt < 4; ++dt) oacc[dt] = (floatx4){0.f, 0.f, 0.f, 0.f};
    float lsum = 0.f;

    for (int kt = 0; kt < 16; ++kt) {
        const int kv0 = kt * 128;
        __syncthreads();
        // K [128 kv][64 dh]: slot i -> (r=i>>3, chunk (i&7)^(r&7))
#pragma unroll
        for (int it = 0; it < 4; ++it) {
            const int i = it * 256 + tid;
            const int r = i >> 3;
            const int c = ((i & 7) ^ (r & 7)) * 8;
            gload_lds16(&qk[(size_t)(tok0 + kv0 + r) * 1024 + 512 + h * 64 + c],
                        &Kt[i * 8]);
        }
        // V^T [64 dh][128 kv]: slot i -> (dh=i>>4, chunk (i&15)^(dh&15))
#pragma unroll
        for (int it = 0; it < 4; ++it) {
            const int i = it * 256 + tid;
            const int dh = i >> 4;
            const int ch = (i & 15) ^ (dh & 15);
            gload_lds16(&vbase[(size_t)dh * 2048 + kv0 + ch * 8], &Vt[i * 8]);
        }
        __syncthreads();

#pragma unroll
        for (int mt = 0; mt < 8; ++mt) {
            const int r = mt * 16 + rl;
            short8 kf0 = *(const short8*)&Kt[r * 64 + ((q4) ^ (r & 7)) * 8];
            short8 kf1 = *(const short8*)&Kt[r * 64 + ((4 + q4) ^ (r & 7)) * 8];
            floatx4 s;
            s = __builtin_amdgcn_mfma_f32_16x16x32_bf16(kf0, qf[0],
                    (floatx4){0.f, 0.f, 0.f, 0.f}, 0, 0, 0);
            s = __builtin_amdgcn_mfma_f32_16x16x32_bf16(kf1, qf[1], s, 0, 0, 0);
            const float p0 = exp2f(s[0]);
            const float p1 = exp2f(s[1]);
            const float p2 = exp2f(s[2]);
            const float p3 = exp2f(s[3]);
            lsum += (p0 + p1) + (p2 + p3);
            const s16x4 pb = pack_p(p0, p1, p2, p3);
            const int ct = 2 * mt + (q4 >> 1);
#pragma unroll
            for (int dt = 0; dt < 4; ++dt) {
                const s16x4 vf = *(const s16x4*)&Vt[(dt * 16 + rl) * 128
                                                    + (ct ^ rl) * 8 + (q4 & 1) * 4];
                oacc[dt] = __builtin_amdgcn_mfma_f32_16x16x16bf16_1k(
                    vf, pb, oacc[dt], 0, 0, 0);
            }
        }
    }

    float l = lsum;
    l += __shfl_xor(l, 16);
    l += __shfl_xor(l, 32);
    const float inv = 1.0f / l;
    const size_t row = tok0 + qrow0 + rl;
#pragma unroll
    for (int dt = 0; dt < 4; ++dt) {
        u16x4 pk;
#pragma unroll
        for (int rr = 0; rr < 4; ++rr) pk[rr] = f2bf(oacc[dt][rr] * inv);
        *(u16x4*)&o[row * DMODEL + h * 64 + dt * 16 + q4 * 4] = pk;
    }
}

// ---------------------------------------------------------------------------
// Router GEMM1 (fp64 accum): rr = gelu(rh @ Rw1^T + Rb1).
// f32 k-major LDS tiles, cvt to f64 in regs. 64x128 block, 4x8/thread.
// ---------------------------------------------------------------------------
__global__ __launch_bounds__(256, 2)
void router_gemm1(const float* __restrict__ A, const float* __restrict__ W,
                  const float* __restrict__ bias, float* __restrict__ out) {
    __shared__ float Af[32][68];
    __shared__ float Bf[32][132];
    const int tid = threadIdx.x;
    const int tx = tid & 15, ty = tid >> 4;
    const int mb = blockIdx.x * 64, nb = blockIdx.y * 128;
    double acc[4][8] = {};
    for (int k0 = 0; k0 < 512; k0 += 32) {
#pragma unroll
        for (int it = 0; it < 2; ++it) {
            const int ch = tid + it * 256;
            const int m = ch >> 3, c4 = (ch & 7) * 4;
            const floatx4 v = *(const floatx4*)&A[(size_t)(mb + m) * 512 + k0 + c4];
#pragma unroll
            for (int e = 0; e < 4; ++e) Af[c4 + e][m] = v[e];
        }
#pragma unroll
        for (int it = 0; it < 4; ++it) {
            const int ch = tid + it * 256;
            const int n = ch >> 3, c4 = (ch & 7) * 4;
            const floatx4 v = *(const floatx4*)&W[(size_t)(nb + n) * 512 + k0 + c4];
#pragma unroll
            for (int e = 0; e < 4; ++e) Bf[c4 + e][n] = v[e];
        }
        __syncthreads();
#pragma unroll 4
        for (int kk = 0; kk < 32; ++kk) {
            const floatx4 a4 = *(const floatx4*)&Af[kk][ty * 4];
            double av[4], bv[8];
#pragma unroll
            for (int i = 0; i < 4; ++i) av[i] = (double)a4[i];
#pragma unroll
            for (int j = 0; j < 8; ++j) bv[j] = (double)Bf[kk][tx + 16 * j];
#pragma unroll
            for (int i = 0; i < 4; ++i)
#pragma unroll
                for (int j = 0; j < 8; ++j)
                    acc[i][j] = fma(av[i], bv[j], acc[i][j]);
        }
        __syncthreads();
    }
#pragma unroll
    for (int i = 0; i < 4; ++i) {
        const int r = mb + ty * 4 + i;
#pragma unroll
        for (int j = 0; j < 8; ++j) {
            const int c = nb + tx + 16 * j;
            out[(size_t)r * 512 + c] = geluf((float)(acc[i][j] + (double)bias[c]));
        }
    }
}

// ---------------------------------------------------------------------------
// Router logits + argmax (fp64): one wave per token.
// ---------------------------------------------------------------------------
__global__ __launch_bounds__(256)
void router_logits_k(const float* __restrict__ rr, const float* __restrict__ Rw2,
                     const float* __restrict__ Rb2, float* __restrict__ logits,
                     float* __restrict__ depthf) {
    const int t = blockIdx.x * 4 + (threadIdx.x >> 6);
    const int lane = threadIdx.x & 63;
    const float* xr = rr + (size_t)t * 512;
    const int c0 = lane * 4, c1 = c0 + 256;
    floatx4 a = *(const floatx4*)&xr[c0];
    floatx4 b = *(const floatx4*)&xr[c1];
    double s[4];
#pragma unroll
    for (int d = 0; d < 4; ++d) {
        const float* wr = Rw2 + d * 512;
        floatx4 wa = *(const floatx4*)&wr[c0];
        floatx4 wb = *(const floatx4*)&wr[c1];
        double acc = 0.0;
#pragma unroll
        for (int e = 0; e < 4; ++e) acc += (double)a[e] * (double)wa[e];
#pragma unroll
        for (int e = 0; e < 4; ++e) acc += (double)b[e] * (double)wb[e];
        s[d] = acc;
    }
#pragma unroll
    for (int m = 32; m >= 1; m >>= 1)
#pragma unroll
        for (int d = 0; d < 4; ++d) s[d] += __shfl_xor(s[d], m);
    if (lane == 0) {
        double bv = -1e300;
        int best = 0;
#pragma unroll
        for (int d = 0; d < 4; ++d) {
            const double v = s[d] + (double)Rb2[d];
            logits[(size_t)t * 4 + d] = (float)v;
            if (v > bv) { bv = v; best = d; }
        }
        depthf[t] = (float)(best + 1);
    }
}

// ---------------------------------------------------------------------------
// Host launcher
// ---------------------------------------------------------------------------
extern "C" void kernel_launch(void* const* d_in, const int* in_sizes, int n_in,
                              void* d_out, int out_size, void* d_ws, size_t ws_size,
                              hipStream_t stream) {
    (void)in_sizes; (void)n_in; (void)out_size; (void)ws_size;
    const float* x    = (const float*)d_in[0];
    const float* ln1g = (const float*)d_in[1];
    const float* ln1b = (const float*)d_in[2];
    const float* Wqkv = (const float*)d_in[3];
    const float* bqkv = (const float*)d_in[4];
    const float* Wo   = (const float*)d_in[5];
    const float* bo   = (const float*)d_in[6];
    const float* ln2g = (const float*)d_in[7];
    const float* ln2b = (const float*)d_in[8];
    const float* W1   = (const float*)d_in[9];
    const float* b1   = (const float*)d_in[10];
    const float* W2   = (const float*)d_in[11];
    const float* b2   = (const float*)d_in[12];
    const float* rng  = (const float*)d_in[13];
    const float* rnb  = (const float*)d_in[14];
    const float* Rw1  = (const float*)d_in[15];
    const float* Rb1  = (const float*)d_in[16];
    const float* Rw2  = (const float*)d_in[17];
    const float* Rb2  = (const float*)d_in[18];

    float* cur    = (float*)d_out;
    float* depthf = cur + (size_t)NTOK * DMODEL;
    float* logits = depthf + NTOK;

    char* ws = (char*)d_ws;
    float* xmid = (float*)ws;                       // 16 MB f32          @ 0
    u16* sbuf   = (u16*)(ws + 16777216);            //  8 MB bf16         @ 16M
    u16* qk     = (u16*)(ws + 25165824);            // 16 MB bf16 (Q|K)   @ 24M
    u16* ffb    = (u16*)(ws + 41943040);            // 32 MB bf16         @ 40M
    u16* vTb    = (u16*)(ws + 75497472);            //  8 MB bf16 V^T     @ 72M
    u16* wbf    = (u16*)(ws + 83886080);            //  6 MB bf16 weights @ 80M
    float* rrf  = (float*)ffb;                      // router temp (pre-level)

    u16* wq = wbf;
    u16* wo = wbf + 786432;
    u16* w1 = wbf + 1048576;
    u16* w2 = wbf + 2097152;

    const float qsc = 0.125f * 1.4426950408889634f;  // (1/sqrt(dh)) * log2(e)

    cvt_w<<<12288, 256, 0, stream>>>(Wqkv, Wo, W1, W2, wbf);
    copy_f32<<<4096, 256, 0, stream>>>(x, cur);

    ln_k<true><<<2048, 256, 0, stream>>>(x, rng, rnb, xmid);
    router_gemm1<<<dim3(128, 4), 256, 0, stream>>>(xmid, Rw1, Rb1, rrf);
    router_logits_k<<<2048, 256, 0, stream>>>(rrf, Rw2, Rb2, logits, depthf);

    for (int level = 1; level <= 4; ++level) {
        ln_k<false><<<2048, 256, 0, stream>>>(cur, ln1g, ln1b, sbuf);
        gemm_bt<0, 128><<<dim3(64, 12), 256, 0, stream>>>(
            sbuf, wq, bqkv, qk, nullptr, nullptr, nullptr, vTb, qsc, 1536, 512);
        attn_k<<<dim3(32, 32), 256, 0, stream>>>(qk, vTb, sbuf);
        gemm_bt<2, 64><<<dim3(64, 8), 256, 0, stream>>>(
            sbuf, wo, bo, nullptr, xmid, cur, nullptr, nullptr, 0.f, 512, 512);
        ln_k<false><<<2048, 256, 0, stream>>>(xmid, ln2g, ln2b, sbuf);
        gemm_bt<1, 128><<<dim3(64, 16), 256, 0, stream>>>(
            sbuf, w1, b1, ffb, nullptr, nullptr, nullptr, nullptr, 0.f, 2048, 512);
        gemm_bt<3, 64><<<dim3(64, 8), 256, 0, stream>>>(
            ffb, w2, b2, nullptr, cur, xmid, depthf, nullptr, (float)level, 512, 2048);
    }
}

// Round 6
// 907.606 us; speedup vs baseline: 1.4666x; 1.0368x over previous
//
#include <hip/hip_runtime.h>

typedef unsigned short u16;
typedef __attribute__((ext_vector_type(8))) short short8;
typedef __attribute__((ext_vector_type(4))) short s16x4;
typedef __attribute__((ext_vector_type(4))) float floatx4;
typedef __attribute__((ext_vector_type(4))) unsigned short u16x4;

#define NTOK 8192
#define DMODEL 512
#define DFF 2048
#define LSEQ 2048
#define RMARGIN 1e-3f

__device__ __forceinline__ u16 f2bf(float f) {
    union { float f; unsigned u; } x; x.f = f;
    unsigned r = (x.u + 0x7fffu + ((x.u >> 16) & 1u)) >> 16;
    return (u16)r;
}
__device__ __forceinline__ float bf2f(u16 h) {
    union { unsigned u; float f; } x; x.u = ((unsigned)h) << 16;
    return x.f;
}

__device__ __forceinline__ float geluf(float x) {
    return 0.5f * x * (1.0f + erff(x * 0.70710678118654752f));
}

__device__ __forceinline__ void gload_lds16(const void* g, void* l) {
    __builtin_amdgcn_global_load_lds(
        (const __attribute__((address_space(1))) void*)g,
        (__attribute__((address_space(3))) void*)l,
        16, 0, 0);
}

// pack 4 f32 -> 4 bf16 (truncation; fine for P in [0,16])
__device__ __forceinline__ s16x4 pack_p(float p0, float p1, float p2, float p3) {
    union { float f; unsigned u; } a{p0}, b{p1}, c{p2}, d{p3};
    union { unsigned u[2]; s16x4 s; } r;
    r.u[0] = (a.u >> 16) | (b.u & 0xffff0000u);
    r.u[1] = (c.u >> 16) | (d.u & 0xffff0000u);
    return r.s;
}

// ---------------------------------------------------------------------------
// Weight f32 -> bf16 conversion (Wqkv | Wo | W1 | W2 packed)
// ---------------------------------------------------------------------------
__global__ __launch_bounds__(256) void cvt_w(const float* __restrict__ wq,
                                             const float* __restrict__ wo,
                                             const float* __restrict__ w1,
                                             const float* __restrict__ w2,
                                             u16* __restrict__ out) {
    int i = blockIdx.x * 256 + threadIdx.x;
    float v;
    if (i < 786432)       v = wq[i];
    else if (i < 1048576) v = wo[i - 786432];
    else if (i < 2097152) v = w1[i - 1048576];
    else                  v = w2[i - 2097152];
    out[i] = f2bf(v);
}

__global__ __launch_bounds__(256) void copy_f32(const float* __restrict__ a,
                                                float* __restrict__ b) {
    size_t i = ((size_t)blockIdx.x * 256 + threadIdx.x) * 4;
    *(floatx4*)&b[i] = *(const floatx4*)&a[i];
}

// ---------------------------------------------------------------------------
// Rw1 split: B' row n (len 1536) = [hi | hi | lo] of Rw1[n][:]
// ---------------------------------------------------------------------------
__global__ __launch_bounds__(256) void cvt_rw1(const float* __restrict__ Rw1,
                                               u16* __restrict__ out) {
    const int i = blockIdx.x * 256 + threadIdx.x;  // 262144
    const int n = i >> 9, k = i & 511;
    const float v = Rw1[i];
    const u16 hi = f2bf(v);
    const u16 lo = f2bf(v - bf2f(hi));
    out[(size_t)n * 1536 + k] = hi;
    out[(size_t)n * 1536 + 512 + k] = hi;
    out[(size_t)n * 1536 + 1024 + k] = lo;
}

// ---------------------------------------------------------------------------
// rh split: A' row t (len 1536) = [hi | lo | hi] of rh[t][:]. Also zeroes cnt.
// ---------------------------------------------------------------------------
__global__ __launch_bounds__(256) void cvt_split(const float* __restrict__ x,
                                                 u16* __restrict__ out,
                                                 int* __restrict__ cnt) {
    if (blockIdx.x == 0 && threadIdx.x == 0) *cnt = 0;
    const int i = blockIdx.x * 256 + threadIdx.x;  // 1048576 quads
    const int base = i * 4;
    const int row = base >> 9, k = base & 511;
    const floatx4 v = *(const floatx4*)&x[base];
    u16x4 h, l;
#pragma unroll
    for (int e = 0; e < 4; ++e) {
        h[e] = f2bf(v[e]);
        l[e] = f2bf(v[e] - bf2f(h[e]));
    }
    u16* o = out + (size_t)row * 1536;
    *(u16x4*)&o[k] = h;
    *(u16x4*)&o[512 + k] = l;
    *(u16x4*)&o[1024 + k] = h;
}

// ---------------------------------------------------------------------------
// LayerNorm over D=512, one wave per row.
// ---------------------------------------------------------------------------
template<bool OUTF32>
__global__ __launch_bounds__(256)
void ln_k(const float* __restrict__ x, const float* __restrict__ g,
          const float* __restrict__ bb, void* __restrict__ outp) {
    const int row = blockIdx.x * 4 + (threadIdx.x >> 6);
    const int lane = threadIdx.x & 63;
    const float* xr = x + (size_t)row * DMODEL;
    const int c0 = lane * 4, c1 = c0 + 256;
    floatx4 a = *(const floatx4*)&xr[c0];
    floatx4 b = *(const floatx4*)&xr[c1];
    float s = 0.f, sq = 0.f;
#pragma unroll
    for (int e = 0; e < 4; ++e) { s += a[e]; sq += a[e] * a[e]; }
#pragma unroll
    for (int e = 0; e < 4; ++e) { s += b[e]; sq += b[e] * b[e]; }
#pragma unroll
    for (int m = 32; m >= 1; m >>= 1) {
        s += __shfl_xor(s, m);
        sq += __shfl_xor(sq, m);
    }
    const float mean = s * (1.f / 512.f);
    const float rstd = rsqrtf(sq * (1.f / 512.f) - mean * mean + 1e-5f);
    floatx4 g0 = *(const floatx4*)&g[c0];
    floatx4 g1 = *(const floatx4*)&g[c1];
    floatx4 b0 = *(const floatx4*)&bb[c0];
    floatx4 b1 = *(const floatx4*)&bb[c1];
    floatx4 y0, y1;
#pragma unroll
    for (int e = 0; e < 4; ++e) {
        y0[e] = (a[e] - mean) * rstd * g0[e] + b0[e];
        y1[e] = (b[e] - mean) * rstd * g1[e] + b1[e];
    }
    if (OUTF32) {
        float* o = (float*)outp + (size_t)row * DMODEL;
        *(floatx4*)&o[c0] = y0;
        *(floatx4*)&o[c1] = y1;
    } else {
        u16* o = (u16*)outp + (size_t)row * DMODEL;
        u16x4 p0, p1;
#pragma unroll
        for (int e = 0; e < 4; ++e) { p0[e] = f2bf(y0[e]); p1[e] = f2bf(y1[e]); }
        *(u16x4*)&o[c0] = p0;
        *(u16x4*)&o[c1] = p1;
    }
}

// ---------------------------------------------------------------------------
// bf16 MFMA GEMM: C[M,N] = epi(A[M,K] @ Bw[N,K]^T + bias)
// EPI: 0 = QKV epilogue (Q scaled, V transposed to Cv)
//      1 = bf16 gelu out
//      2 = f32 out = res + v
//      3 = f32 out = keep ? res + v : old   (keep = depth[row] >= aux)
//      4 = f32 out = gelu(v)      (router pass-1)
// ---------------------------------------------------------------------------
template<int EPI, int BN>
__global__ __launch_bounds__(256, 2)
void gemm_bt(const u16* __restrict__ A, const u16* __restrict__ Bw,
             const float* __restrict__ bias,
             u16* __restrict__ Cb, float* __restrict__ Cf,
             const float* __restrict__ res, const float* __restrict__ depth,
             u16* __restrict__ Cv,
             float aux, int N, int K) {
    constexpr int NJ = BN / 32;
    __shared__ __align__(16) u16 As[128 * 32];
    __shared__ __align__(16) u16 Bs[BN * 32];
    const int tid = threadIdx.x;
    const int lane = tid & 63;
    const int w = tid >> 6;
    const int wm = (w >> 1) * 64;
    const int wn = (w & 1) * (BN / 2);
    const int mBase = blockIdx.x * 128;
    const int nBase = blockIdx.y * BN;
    const int q4 = lane >> 4, rl = lane & 15;

    floatx4 acc[4][NJ];
#pragma unroll
    for (int i = 0; i < 4; ++i)
#pragma unroll
        for (int j = 0; j < NJ; ++j) acc[i][j] = (floatx4){0.f, 0.f, 0.f, 0.f};

    const int i0 = tid, i1 = tid + 256;
    const int ar0 = i0 >> 2, ac0 = ((i0 & 3) ^ ((i0 >> 3) & 3)) * 8;
    const int ar1 = i1 >> 2, ac1 = ((i1 & 3) ^ ((i1 >> 3) & 3)) * 8;
    const u16* pA0 = A + (size_t)(mBase + ar0) * K + ac0;
    const u16* pA1 = A + (size_t)(mBase + ar1) * K + ac1;
    const u16* pB0 = Bw + (size_t)(nBase + ar0) * K + ac0;
    const u16* pB1 = (BN == 128) ? Bw + (size_t)(nBase + ar1) * K + ac1 : pB0;
    u16* lA0 = &As[i0 * 8];
    u16* lA1 = &As[i1 * 8];
    u16* lB0 = &Bs[i0 * 8];
    u16* lB1 = (BN == 128) ? &Bs[i1 * 8] : lB0;

    for (int k0 = 0; k0 < K; k0 += 32) {
        gload_lds16(pA0, lA0);
        gload_lds16(pA1, lA1);
        gload_lds16(pB0, lB0);
        if (BN == 128) gload_lds16(pB1, lB1);
        pA0 += 32; pA1 += 32; pB0 += 32;
        if (BN == 128) pB1 += 32;
        __syncthreads();
        short8 af[4], bf[NJ];
#pragma unroll
        for (int t = 0; t < 4; ++t) {
            const int r = wm + t * 16 + rl;
            af[t] = *(const short8*)&As[r * 32 + (q4 ^ ((r >> 1) & 3)) * 8];
        }
#pragma unroll
        for (int t = 0; t < NJ; ++t) {
            const int r = wn + t * 16 + rl;
            bf[t] = *(const short8*)&Bs[r * 32 + (q4 ^ ((r >> 1) & 3)) * 8];
        }
#pragma unroll
        for (int ti = 0; ti < 4; ++ti)
#pragma unroll
            for (int tj = 0; tj < NJ; ++tj)
                acc[ti][tj] = __builtin_amdgcn_mfma_f32_16x16x32_bf16(
                    af[ti], bf[tj], acc[ti][tj], 0, 0, 0);
        __syncthreads();
    }

#pragma unroll
    for (int ti = 0; ti < 4; ++ti) {
        const int r0 = mBase + wm + ti * 16 + q4 * 4;
#pragma unroll
        for (int tj = 0; tj < NJ; ++tj) {
            const int c = nBase + wn + tj * 16 + rl;
            const float bv = bias[c];
            if (EPI == 0) {
                if (nBase < 1024) {
                    const float sc = (nBase < 512) ? aux : 1.0f;
#pragma unroll
                    for (int rr = 0; rr < 4; ++rr)
                        Cb[(size_t)(r0 + rr) * 1024 + c] =
                            f2bf((acc[ti][tj][rr] + bv) * sc);
                } else {
                    const int cm = c - 1024;
                    const int hh = cm >> 6, dh = cm & 63;
                    const int bb2 = r0 >> 11, kv = r0 & 2047;
                    u16x4 pk;
#pragma unroll
                    for (int rr = 0; rr < 4; ++rr)
                        pk[rr] = f2bf(acc[ti][tj][rr] + bv);
                    *(u16x4*)&Cv[((size_t)(bb2 * 8 + hh) * 64 + dh) * 2048 + kv] = pk;
                }
            } else {
#pragma unroll
                for (int rr = 0; rr < 4; ++rr) {
                    const int r = r0 + rr;
                    const float v = acc[ti][tj][rr] + bv;
                    if (EPI == 1) {
                        Cb[(size_t)r * N + c] = f2bf(geluf(v));
                    } else if (EPI == 2) {
                        Cf[(size_t)r * N + c] = res[(size_t)r * N + c] + v;
                    } else if (EPI == 3) {
                        if (depth[r] >= aux)
                            Cf[(size_t)r * N + c] = res[(size_t)r * N + c] + v;
                    } else {
                        Cf[(size_t)r * N + c] = geluf(v);
                    }
                }
            }
        }
    }
}

// ---------------------------------------------------------------------------
// Flash attention via S^T (register-resident P^T). 64 q-rows/block.
// ---------------------------------------------------------------------------
__global__ __launch_bounds__(256, 4)
void attn_k(const u16* __restrict__ qk, const u16* __restrict__ vT,
            u16* __restrict__ o) {
    const int qt = blockIdx.x;
    const int bh = blockIdx.y;
    const int b = bh >> 3, h = bh & 7;
    const int tid = threadIdx.x, lane = tid & 63, w = tid >> 6;
    const int tok0 = b * LSEQ;
    const int qrow0 = qt * 64 + w * 16;
    const int q4 = lane >> 4, rl = lane & 15;

    __shared__ __align__(16) u16 Kt[128 * 64];
    __shared__ __align__(16) u16 Vt[64 * 128];

    const u16* vbase = vT + (size_t)bh * 64 * 2048;

    short8 qf[2];
#pragma unroll
    for (int ks = 0; ks < 2; ++ks)
        qf[ks] = *(const short8*)&qk[(size_t)(tok0 + qrow0 + rl) * 1024
                                      + h * 64 + ks * 32 + q4 * 8];

    floatx4 oacc[4];
#pragma unroll
    for (int dt = 0; dt < 4; ++dt) oacc[dt] = (floatx4){0.f, 0.f, 0.f, 0.f};
    float lsum = 0.f;

    for (int kt = 0; kt < 16; ++kt) {
        const int kv0 = kt * 128;
        __syncthreads();
#pragma unroll
        for (int it = 0; it < 4; ++it) {
            const int i = it * 256 + tid;
            const int r = i >> 3;
            const int c = ((i & 7) ^ (r & 7)) * 8;
            gload_lds16(&qk[(size_t)(tok0 + kv0 + r) * 1024 + 512 + h * 64 + c],
                        &Kt[i * 8]);
        }
#pragma unroll
        for (int it = 0; it < 4; ++it) {
            const int i = it * 256 + tid;
            const int dh = i >> 4;
            const int ch = (i & 15) ^ (dh & 15);
            gload_lds16(&vbase[(size_t)dh * 2048 + kv0 + ch * 8], &Vt[i * 8]);
        }
        __syncthreads();

#pragma unroll
        for (int mt = 0; mt < 8; ++mt) {
            const int r = mt * 16 + rl;
            short8 kf0 = *(const short8*)&Kt[r * 64 + ((q4) ^ (r & 7)) * 8];
            short8 kf1 = *(const short8*)&Kt[r * 64 + ((4 + q4) ^ (r & 7)) * 8];
            floatx4 s;
            s = __builtin_amdgcn_mfma_f32_16x16x32_bf16(kf0, qf[0],
                    (floatx4){0.f, 0.f, 0.f, 0.f}, 0, 0, 0);
            s = __builtin_amdgcn_mfma_f32_16x16x32_bf16(kf1, qf[1], s, 0, 0, 0);
            const float p0 = exp2f(s[0]);
            const float p1 = exp2f(s[1]);
            const float p2 = exp2f(s[2]);
            const float p3 = exp2f(s[3]);
            lsum += (p0 + p1) + (p2 + p3);
            const s16x4 pb = pack_p(p0, p1, p2, p3);
            const int ct = 2 * mt + (q4 >> 1);
#pragma unroll
            for (int dt = 0; dt < 4; ++dt) {
                const s16x4 vf = *(const s16x4*)&Vt[(dt * 16 + rl) * 128
                                                    + (ct ^ rl) * 8 + (q4 & 1) * 4];
                oacc[dt] = __builtin_amdgcn_mfma_f32_16x16x16bf16_1k(
                    vf, pb, oacc[dt], 0, 0, 0);
            }
        }
    }

    float l = lsum;
    l += __shfl_xor(l, 16);
    l += __shfl_xor(l, 32);
    const float inv = 1.0f / l;
    const size_t row = tok0 + qrow0 + rl;
#pragma unroll
    for (int dt = 0; dt < 4; ++dt) {
        u16x4 pk;
#pragma unroll
        for (int rr = 0; rr < 4; ++rr) pk[rr] = f2bf(oacc[dt][rr] * inv);
        *(u16x4*)&o[row * DMODEL + h * 64 + dt * 16 + q4 * 4] = pk;
    }
}

// ---------------------------------------------------------------------------
// Router logits pass-1 (f32, from split-bf16 GEMM rr): one wave per token.
// Flags tokens whose top-2 gap < RMARGIN for exact f64 recheck.
// ---------------------------------------------------------------------------
__global__ __launch_bounds__(256)
void router_logits_f32(const float* __restrict__ rr, const float* __restrict__ Rw2,
                       const float* __restrict__ Rb2, float* __restrict__ logits,
                       float* __restrict__ depthf, int* __restrict__ cnt,
                       int* __restrict__ list) {
    const int t = blockIdx.x * 4 + (threadIdx.x >> 6);
    const int lane = threadIdx.x & 63;
    const float* xr = rr + (size_t)t * 512;
    const int c0 = lane * 4, c1 = c0 + 256;
    floatx4 a = *(const floatx4*)&xr[c0];
    floatx4 b = *(const floatx4*)&xr[c1];
    float s[4];
#pragma unroll
    for (int d = 0; d < 4; ++d) {
        const float* wr = Rw2 + d * 512;
        floatx4 wa = *(const floatx4*)&wr[c0];
        floatx4 wb = *(const floatx4*)&wr[c1];
        float acc = 0.f;
#pragma unroll
        for (int e = 0; e < 4; ++e) acc += a[e] * wa[e];
#pragma unroll
        for (int e = 0; e < 4; ++e) acc += b[e] * wb[e];
        s[d] = acc;
    }
#pragma unroll
    for (int m = 32; m >= 1; m >>= 1)
#pragma unroll
        for (int d = 0; d < 4; ++d) s[d] += __shfl_xor(s[d], m);
    if (lane == 0) {
        float v[4];
        float bv = -1e30f; int best = 0;
#pragma unroll
        for (int d = 0; d < 4; ++d) {
            v[d] = s[d] + Rb2[d];
            logits[(size_t)t * 4 + d] = v[d];
            if (v[d] > bv) { bv = v[d]; best = d; }
        }
        float second = -1e30f;
#pragma unroll
        for (int d = 0; d < 4; ++d)
            if (d != best) second = fmaxf(second, v[d]);
        depthf[t] = (float)(best + 1);
        if (bv - second < RMARGIN) {
            int idx = atomicAdd(cnt, 1);
            list[idx] = t;
        }
    }
}

// ---------------------------------------------------------------------------
// Exact f64 router recheck for flagged tokens (gather).
// ---------------------------------------------------------------------------
__global__ __launch_bounds__(256)
void router_exact(const float* __restrict__ rh, const float* __restrict__ Rw1,
                  const float* __restrict__ Rb1, const float* __restrict__ Rw2,
                  const float* __restrict__ Rb2, const int* __restrict__ cnt,
                  const int* __restrict__ list, float* __restrict__ logits,
                  float* __restrict__ depthf) {
    __shared__ float rhs[512];
    __shared__ double rrd[512];
    __shared__ double lg[4];
    const int n = *cnt;
    const int tid = threadIdx.x;
    for (int ii = blockIdx.x; ii < n; ii += gridDim.x) {
        const int t = list[ii];
        rhs[tid] = rh[(size_t)t * 512 + tid];
        rhs[tid + 256] = rh[(size_t)t * 512 + 256 + tid];
        __syncthreads();
#pragma unroll
        for (int oo = 0; oo < 2; ++oo) {
            const int nn = tid + oo * 256;
            double acc = (double)Rb1[nn];
            const float* wrow = Rw1 + (size_t)nn * 512;
            for (int k = 0; k < 512; ++k)
                acc = fma((double)rhs[k], (double)wrow[k], acc);
            rrd[nn] = 0.5 * acc * (1.0 + erf(acc * 0.70710678118654752440));
        }
        __syncthreads();
        const int w = tid >> 6, lane = tid & 63;
        double acc2 = 0.0;
        for (int k = lane; k < 512; k += 64)
            acc2 += rrd[k] * (double)Rw2[w * 512 + k];
#pragma unroll
        for (int m = 32; m >= 1; m >>= 1) acc2 += __shfl_xor(acc2, m);
        if (lane == 0) lg[w] = acc2 + (double)Rb2[w];
        __syncthreads();
        if (tid == 0) {
            double bv = -1e300; int best = 0;
#pragma unroll
            for (int d = 0; d < 4; ++d) {
                const double v = lg[d];
                logits[(size_t)t * 4 + d] = (float)v;
                if (v > bv) { bv = v; best = d; }
            }
            depthf[t] = (float)(best + 1);
        }
        __syncthreads();
    }
}

// ---------------------------------------------------------------------------
// Host launcher
// ---------------------------------------------------------------------------
extern "C" void kernel_launch(void* const* d_in, const int* in_sizes, int n_in,
                              void* d_out, int out_size, void* d_ws, size_t ws_size,
                              hipStream_t stream) {
    (void)in_sizes; (void)n_in; (void)out_size; (void)ws_size;
    const float* x    = (const float*)d_in[0];
    const float* ln1g = (const float*)d_in[1];
    const float* ln1b = (const float*)d_in[2];
    const float* Wqkv = (const float*)d_in[3];
    const float* bqkv = (const float*)d_in[4];
    const float* Wo   = (const float*)d_in[5];
    const float* bo   = (const float*)d_in[6];
    const float* ln2g = (const float*)d_in[7];
    const float* ln2b = (const float*)d_in[8];
    const float* W1   = (const float*)d_in[9];
    const float* b1   = (const float*)d_in[10];
    const float* W2   = (const float*)d_in[11];
    const float* b2   = (const float*)d_in[12];
    const float* rng  = (const float*)d_in[13];
    const float* rnb  = (const float*)d_in[14];
    const float* Rw1  = (const float*)d_in[15];
    const float* Rb1  = (const float*)d_in[16];
    const float* Rw2  = (const float*)d_in[17];
    const float* Rb2  = (const float*)d_in[18];

    float* cur    = (float*)d_out;
    float* depthf = cur + (size_t)NTOK * DMODEL;
    float* logits = depthf + NTOK;

    char* ws = (char*)d_ws;
    float* xmid = (float*)ws;                       // 16 MB f32          @ 0
    u16* sbuf   = (u16*)(ws + 16777216);            //  8 MB bf16         @ 16M
    u16* qk     = (u16*)(ws + 25165824);            // 16 MB bf16 (Q|K)   @ 24M
    u16* ffb    = (u16*)(ws + 41943040);            // 32 MB bf16         @ 40M
    u16* vTb    = (u16*)(ws + 75497472);            //  8 MB bf16 V^T     @ 72M
    u16* wbf    = (u16*)(ws + 83886080);            //  6 MB bf16 weights @ 80M

    // router-phase aliases (all dead before the level loop runs)
    u16* rw1s   = (u16*)(ws + 16777216);            // 1.5 MB B' split    @ 16M (sbuf)
    int* rcnt   = (int*)(ws + 18874368);            // counter            @ 18M
    int* rlist  = rcnt + 16;                        // flagged tokens
    u16* asplit = ffb;                              // 25.2 MB A' split   @ 40M
    float* rrf  = (float*)qk;                       // 16 MB rr f32       @ 24M

    u16* wq = wbf;
    u16* wo = wbf + 786432;
    u16* w1 = wbf + 1048576;
    u16* w2 = wbf + 2097152;

    const float qsc = 0.125f * 1.4426950408889634f;  // (1/sqrt(dh)) * log2(e)

    cvt_w<<<12288, 256, 0, stream>>>(Wqkv, Wo, W1, W2, wbf);
    copy_f32<<<4096, 256, 0, stream>>>(x, cur);

    // --- router: split-bf16 pass-1 + exact f64 recheck of near-ties ---
    ln_k<true><<<2048, 256, 0, stream>>>(x, rng, rnb, xmid);
    cvt_rw1<<<1024, 256, 0, stream>>>(Rw1, rw1s);
    cvt_split<<<4096, 256, 0, stream>>>(xmid, asplit, rcnt);
    gemm_bt<4, 64><<<dim3(64, 8), 256, 0, stream>>>(
        asplit, rw1s, Rb1, nullptr, rrf, nullptr, nullptr, nullptr, 0.f, 512, 1536);
    router_logits_f32<<<2048, 256, 0, stream>>>(rrf, Rw2, Rb2, logits, depthf,
                                                rcnt, rlist);
    router_exact<<<128, 256, 0, stream>>>(xmid, Rw1, Rb1, Rw2, Rb2, rcnt, rlist,
                                          logits, depthf);

    // --- 4 recursion levels ---
    for (int level = 1; level <= 4; ++level) {
        ln_k<false><<<2048, 256, 0, stream>>>(cur, ln1g, ln1b, sbuf);
        gemm_bt<0, 128><<<dim3(64, 12), 256, 0, stream>>>(
            sbuf, wq, bqkv, qk, nullptr, nullptr, nullptr, vTb, qsc, 1536, 512);
        attn_k<<<dim3(32, 32), 256, 0, stream>>>(qk, vTb, sbuf);
        gemm_bt<2, 64><<<dim3(64, 8), 256, 0, stream>>>(
            sbuf, wo, bo, nullptr, xmid, cur, nullptr, nullptr, 0.f, 512, 512);
        ln_k<false><<<2048, 256, 0, stream>>>(xmid, ln2g, ln2b, sbuf);
        gemm_bt<1, 128><<<dim3(64, 16), 256, 0, stream>>>(
            sbuf, w1, b1, ffb, nullptr, nullptr, nullptr, nullptr, 0.f, 2048, 512);
        gemm_bt<3, 64><<<dim3(64, 8), 256, 0, stream>>>(
            ffb, w2, b2, nullptr, cur, xmid, depthf, nullptr, (float)level, 512, 2048);
    }
}